// Round 4
// baseline (171.046 us; speedup 1.0000x reference)
//
#include <hip/hip_runtime.h>
#include <hip/hip_bf16.h>
#include <math.h>

using bf16 = __hip_bfloat16;
typedef __bf16 bf16x8 __attribute__((ext_vector_type(8)));
typedef float floatx4 __attribute__((ext_vector_type(4)));

// Problem dims
constexpr int BB = 4, SS = 2048, DIN = 512, DKK = 2048, DVV = 64;
constexpr int ROWS = BB * SS;          // 8192
constexpr int LDY = 640;               // yv row: y(512) | pad(128, garbage ok)

// ---- workspace layout (bytes) ----
constexpr size_t XB_OFF  = 0;                          // bf16 xb  [8192][512]   (8 MB)
constexpr size_t WQB_OFF = XB_OFF  + 8388608;          // bf16 wqb [512][2048]   (2 MB)
constexpr size_t WKB_OFF = WQB_OFF + 2097152;          // bf16 wkb [512][2048]   (2 MB)
constexpr size_t WT2_OFF = WKB_OFF + 2097152;          // bf16 wt2 [640][512]
constexpr size_t MTP_OFF = WT2_OFF + 655360;           // fp32 mt partials [8][512][512] (8 MB)
constexpr size_t YV_OFF  = MTP_OFF + 8388608;          // bf16 yv  [8192][640]   (10 MB)
constexpr size_t VT_OFF  = YV_OFF  + 10485760;         // bf16 vt  [4][64][2048] (1 MB)
constexpr size_t PRT_OFF = VT_OFF  + 1048576;          // bf16 O' partials [4][16][2048][64] (16 MB)
constexpr size_t STA_OFF = PRT_OFF + 16777216;         // fp32 stats [4][16][2048][2] (1 MB)

__device__ __forceinline__ void async_copy16(const bf16* g, const unsigned short* l) {
    __builtin_amdgcn_global_load_lds((const __attribute__((address_space(1))) void*)g,
                                     (__attribute__((address_space(3))) void*)l, 16, 0, 0);
}

// ---------------- fused prep: convert x | convert Wq,Wk | transpose Wv ----------------
__global__ __launch_bounds__(256) void prep(const float* __restrict__ x,
                                            const float* __restrict__ Wq,
                                            const float* __restrict__ Wk,
                                            const float* __restrict__ Wv,
                                            bf16* __restrict__ xb,
                                            bf16* __restrict__ wqb,
                                            bf16* __restrict__ wkb,
                                            bf16* __restrict__ wt2) {
    __shared__ float tile[32][33];
    const int bid = blockIdx.x;
    const int tid = threadIdx.x;

    if (bid < 4096) {
        int i = bid * 256 + tid;                     // over 1048576 float4 groups
        float4 v = reinterpret_cast<const float4*>(x)[i];
        union { bf16 h[4]; ushort4 u; } cv;
        cv.h[0] = __float2bfloat16(v.x);
        cv.h[1] = __float2bfloat16(v.y);
        cv.h[2] = __float2bfloat16(v.z);
        cv.h[3] = __float2bfloat16(v.w);
        reinterpret_cast<ushort4*>(xb)[i] = cv.u;
    } else if (bid < 6144) {
        int i = (bid - 4096) * 256 + tid;            // over 524288 float4 groups
        const float* src = (i < 262144) ? Wq : Wk;
        bf16* dst = (i < 262144) ? wqb : wkb;
        int j = (i < 262144) ? i : i - 262144;
        float4 v = reinterpret_cast<const float4*>(src)[j];
        union { bf16 h[4]; ushort4 u; } cv;
        cv.h[0] = __float2bfloat16(v.x);
        cv.h[1] = __float2bfloat16(v.y);
        cv.h[2] = __float2bfloat16(v.z);
        cv.h[3] = __float2bfloat16(v.w);
        reinterpret_cast<ushort4*>(dst)[j] = cv.u;
    } else {
        int idx = bid - 6144;                        // 0..31
        int n0 = (idx & 1) * 32;
        int k0 = (idx >> 1) * 32;
        int nn = tid & 31, kk8 = tid >> 5;
        #pragma unroll
        for (int p = 0; p < 4; ++p) {
            int k = p * 8 + kk8;
            tile[k][nn] = Wv[(long long)(k0 + k) * 64 + n0 + nn];
        }
        __syncthreads();
        int kk = tid & 31, nn8 = tid >> 5;
        #pragma unroll
        for (int p = 0; p < 4; ++p) {
            int n = p * 8 + nn8;
            wt2[(long long)(512 + n0 + n) * 512 + k0 + kk] = __float2bfloat16(tile[kk][n]);
        }
    }
}

// ---------------- Mt partial GEMM: Mt[j][i] = sum_n wkb[j][n]*wqb[i][n], split-K 8 ----------------
__global__ __launch_bounds__(256) void gemm_mt(const bf16* __restrict__ A,
                                               const bf16* __restrict__ Bt,
                                               float* __restrict__ Cp) {
    __shared__ __align__(16) unsigned short As[128 * 64];
    __shared__ __align__(16) unsigned short Bs[128 * 64];

    const int tid = threadIdx.x;
    const int lane = tid & 63, wave = tid >> 6;

    // bijective XCD swizzle: 128 blocks, q = 16
    const int wg = (blockIdx.x & 7) * 16 + (blockIdx.x >> 3);
    const int z = wg >> 4;               // split-K plane 0..7
    const int tile = wg & 15;
    const long long m0 = (long long)(tile >> 2) * 128;
    const long long n0 = (long long)(tile & 3) * 128;
    const int koff = z * 256;

    const int rIn = lane >> 3;
    const int cSwz = ((lane & 7) ^ rIn) * 8;
    const int wm0 = (wave >> 1) * 64, wn0 = (wave & 1) * 64;
    const int l15 = lane & 15, quad = lane >> 4;
    const int sw7 = l15 & 7;

    floatx4 acc[4][4] = {};

    for (int k0 = koff; k0 < koff + 256; k0 += 64) {
        #pragma unroll
        for (int t0 = 0; t0 < 8; ++t0) {
            int t = t0 * 4 + wave;
            if (t < 16)
                async_copy16(A + (m0 + t * 8 + rIn) * 2048LL + k0 + cSwz, &As[t * 512]);
            else
                async_copy16(Bt + (n0 + (t - 16) * 8 + rIn) * 2048LL + k0 + cSwz, &Bs[(t - 16) * 512]);
        }
        __syncthreads();
        #pragma unroll
        for (int sk = 0; sk < 2; ++sk) {
            const int rchunk = (((sk << 2) | quad) ^ sw7) * 8;
            bf16x8 af[4], bfr[4];
            #pragma unroll
            for (int mi = 0; mi < 4; ++mi)
                af[mi] = *reinterpret_cast<const bf16x8*>(&As[(wm0 + mi * 16 + l15) * 64 + rchunk]);
            #pragma unroll
            for (int ni = 0; ni < 4; ++ni)
                bfr[ni] = *reinterpret_cast<const bf16x8*>(&Bs[(wn0 + ni * 16 + l15) * 64 + rchunk]);
            #pragma unroll
            for (int mi = 0; mi < 4; ++mi)
                #pragma unroll
                for (int ni = 0; ni < 4; ++ni)
                    acc[mi][ni] = __builtin_amdgcn_mfma_f32_16x16x32_bf16(af[mi], bfr[ni],
                                                                          acc[mi][ni], 0, 0, 0);
        }
        __syncthreads();
    }

    float* C = Cp + (long long)z * 262144;
    #pragma unroll
    for (int mi = 0; mi < 4; ++mi) {
        long long row0 = m0 + wm0 + mi * 16 + quad * 4;
        #pragma unroll
        for (int ni = 0; ni < 4; ++ni) {
            long long col = n0 + wn0 + ni * 16 + l15;
            #pragma unroll
            for (int r = 0; r < 4; ++r)
                C[(row0 + r) * 512 + col] = acc[mi][ni][r];
        }
    }
}

// ---------------- reduce Mt partials -> wt2 rows 0..511 (bf16) ----------------
__global__ __launch_bounds__(256) void reduce_mt(const float4* __restrict__ part,
                                                 bf16* __restrict__ wt2) {
    int i = blockIdx.x * 256 + threadIdx.x;          // over 65536 float4 groups
    float4 s = {0.f, 0.f, 0.f, 0.f};
    #pragma unroll
    for (int t = 0; t < 8; ++t) {
        float4 a = part[(long long)t * 65536 + i];
        s.x += a.x; s.y += a.y; s.z += a.z; s.w += a.w;
    }
    union { bf16 h[4]; ushort4 u; } cv;
    cv.h[0] = __float2bfloat16(s.x);
    cv.h[1] = __float2bfloat16(s.y);
    cv.h[2] = __float2bfloat16(s.z);
    cv.h[3] = __float2bfloat16(s.w);
    reinterpret_cast<ushort4*>(wt2)[i] = cv.u;
}

// ---------------- yv GEMM: yv[8192][0..512) = xb . wt2^T, K=512 ----------------
__global__ __launch_bounds__(256) void gemm_proj(const bf16* __restrict__ A,
                                                 const bf16* __restrict__ Bt,
                                                 bf16* __restrict__ C,
                                                 bf16* __restrict__ vt) {
    __shared__ __align__(16) unsigned short As[128 * 64];
    __shared__ __align__(16) unsigned short Bs[128 * 64];

    const int tid = threadIdx.x;
    const int lane = tid & 63, wave = tid >> 6;

    // bijective XCD swizzle: 320 blocks, q = 40; m-major enumeration
    const int wg = (blockIdx.x & 7) * 40 + (blockIdx.x >> 3);
    const long long m0 = (long long)(wg / 5) * 128;
    const long long n0 = (long long)(wg % 5) * 128;

    const int rIn = lane >> 3;
    const int cSwz = ((lane & 7) ^ rIn) * 8;
    const int wm0 = (wave >> 1) * 64, wn0 = (wave & 1) * 64;
    const int l15 = lane & 15, quad = lane >> 4;
    const int sw7 = l15 & 7;

    floatx4 acc[4][4] = {};

    for (int k0 = 0; k0 < DIN; k0 += 64) {
        #pragma unroll
        for (int t0 = 0; t0 < 8; ++t0) {
            int t = t0 * 4 + wave;
            if (t < 16)
                async_copy16(A + (m0 + t * 8 + rIn) * (long long)DIN + k0 + cSwz, &As[t * 512]);
            else
                async_copy16(Bt + (n0 + (t - 16) * 8 + rIn) * (long long)DIN + k0 + cSwz, &Bs[(t - 16) * 512]);
        }
        __syncthreads();
        #pragma unroll
        for (int sk = 0; sk < 2; ++sk) {
            const int rchunk = (((sk << 2) | quad) ^ sw7) * 8;
            bf16x8 af[4], bfr[4];
            #pragma unroll
            for (int mi = 0; mi < 4; ++mi)
                af[mi] = *reinterpret_cast<const bf16x8*>(&As[(wm0 + mi * 16 + l15) * 64 + rchunk]);
            #pragma unroll
            for (int ni = 0; ni < 4; ++ni)
                bfr[ni] = *reinterpret_cast<const bf16x8*>(&Bs[(wn0 + ni * 16 + l15) * 64 + rchunk]);
            #pragma unroll
            for (int mi = 0; mi < 4; ++mi)
                #pragma unroll
                for (int ni = 0; ni < 4; ++ni)
                    acc[mi][ni] = __builtin_amdgcn_mfma_f32_16x16x32_bf16(af[mi], bfr[ni],
                                                                          acc[mi][ni], 0, 0, 0);
        }
        __syncthreads();
    }

    if (n0 < 512) {
        // y columns -> yv (row stride LDY)
        #pragma unroll
        for (int mi = 0; mi < 4; ++mi) {
            long long row0 = m0 + wm0 + mi * 16 + quad * 4;
            #pragma unroll
            for (int ni = 0; ni < 4; ++ni) {
                long long col = n0 + wn0 + ni * 16 + l15;
                #pragma unroll
                for (int r = 0; r < 4; ++r)
                    C[(row0 + r) * (long long)LDY + col] = __float2bfloat16(acc[mi][ni][r]);
            }
        }
    } else if (!(wave & 1)) {
        // v columns (j = ni*16+l15 in [0,64)) -> vt[b][j][s] transposed
        const int b = (int)(m0 >> 11);
        const int sbase = ((int)m0 & 2047) + wm0;
        #pragma unroll
        for (int mi = 0; mi < 4; ++mi) {
            int s0 = sbase + mi * 16 + quad * 4;
            #pragma unroll
            for (int ni = 0; ni < 4; ++ni) {
                int j = ni * 16 + l15;
                union { bf16 h[4]; ushort4 u; } cv;
                #pragma unroll
                for (int r = 0; r < 4; ++r)
                    cv.h[r] = __float2bfloat16(acc[mi][ni][r]);
                *reinterpret_cast<ushort4*>(vt + ((long long)(b * DVV + j)) * SS + s0) = cv.u;
            }
        }
    }
}

// ---------------- fused causal attention tile, M=256 x N=128 (K=512: scores = y·x^T) ------------
// 72 causal tiles per batch (by in [0,8) panels of 256 rows; bx in [0, 2(by+1)) 128-col k-tiles).
// Per K-iter: 32 MFMA/wave amortize each vmcnt-drain (2x the 128-row version), drain-iters
// 4352 -> 2304 total. PV split in two 64-col K-halves, chunk order 0,1,2,3 (bit-identical).
__global__ __launch_bounds__(512) void attn_fused(const bf16* __restrict__ yv,
                                                  const bf16* __restrict__ xb,
                                                  const bf16* __restrict__ vt,
                                                  bf16* __restrict__ part,
                                                  float* __restrict__ stats) {
    constexpr int BK = 64;
    constexpr float SCALE = 0.022097086912079608f;   // 1/sqrt(2048)

    __shared__ __align__(16) char smem[55296];
    unsigned short* As = (unsigned short*)smem;             // [32*512] QK A staging (32 KB, 256 rows)
    unsigned short* Bs = (unsigned short*)(smem + 32768);   // [16*512] QK B staging (16 KB, 128 rows)
    unsigned short* Ps = (unsigned short*)smem;             // [256][66] P~ half (overlay, post-QK)
    float* smax = (float*)(smem + 33792);                   // [256][2]
    float* ssum = (float*)(smem + 35840);                   // [256][2]
    unsigned short* Vs = (unsigned short*)(smem + 37888);   // [64][136] V chunk

    // causal tile decode: 72 = 8 * 9 bijective XCD swizzle
    const int wg = (blockIdx.x & 7) * 9 + (blockIdx.x >> 3);
    int by = 0;
    while ((by + 1) * (by + 2) <= wg) ++by;      // panels: tiles before panel p = p(p+1)
    const int bx = wg - by * (by + 1);
    const int b = blockIdx.z;

    const bf16* A  = yv + (long long)b * SS * LDY;           // y rows (q role)
    const bf16* Bt = xb + (long long)b * SS * 512;           // x rows (k role)

    const int tid = threadIdx.x;
    const int lane = tid & 63, wave = tid >> 6;
    const long long m0 = (long long)by * 256;
    const long long n0 = (long long)bx * 128;

    const int rIn = lane >> 3;
    const int cSwz = ((lane & 7) ^ rIn) * 8;
    const int wm0 = (wave >> 1) * 64, wn0 = (wave & 1) * 64;
    const int l15 = lane & 15, quad = lane >> 4;
    const int sw7 = l15 & 7;

    floatx4 acc[4][4] = {};

    // T14: prefetch V chunk to registers (ds_write after QK when Vs overlay is free)
    uint4 vreg[2];
    #pragma unroll
    for (int p = 0; p < 2; ++p) {
        int j = (tid >> 4) + p * 32;
        int ch = tid & 15;
        vreg[p] = *reinterpret_cast<const uint4*>(
            vt + ((long long)b * DVV + j) * SS + n0 + ch * 8);
    }

    auto issue = [&](int k0) {
        #pragma unroll
        for (int t0 = 0; t0 < 6; ++t0) {             // 48 slots: 32 A (256 rows) + 16 B (128 rows)
            int t = t0 * 8 + wave;
            if (t < 32)
                async_copy16(A + (m0 + t * 8 + rIn) * (long long)LDY + k0 + cSwz,
                             &As[t * 512]);
            else
                async_copy16(Bt + (n0 + (t - 32) * 8 + rIn) * 512LL + k0 + cSwz,
                             &Bs[(t - 32) * 512]);
        }
    };

    for (int it = 0; it < DIN / BK; ++it) {      // 8 iterations (K=512)
        issue(it * BK);
        __syncthreads();                          // loads landed (compiler drains vmcnt)
        __builtin_amdgcn_s_setprio(1);
        #pragma unroll
        for (int sk = 0; sk < 2; ++sk) {
            const int rchunk = (((sk << 2) | quad) ^ sw7) * 8;
            bf16x8 af[4], bfr[4];
            #pragma unroll
            for (int mi = 0; mi < 4; ++mi)
                af[mi] = *reinterpret_cast<const bf16x8*>(
                    &As[(wm0 + mi * 16 + l15) * BK + rchunk]);
            #pragma unroll
            for (int ni = 0; ni < 4; ++ni)
                bfr[ni] = *reinterpret_cast<const bf16x8*>(
                    &Bs[(wn0 + ni * 16 + l15) * BK + rchunk]);
            #pragma unroll
            for (int mi = 0; mi < 4; ++mi)
                #pragma unroll
                for (int ni = 0; ni < 4; ++ni)
                    acc[mi][ni] = __builtin_amdgcn_mfma_f32_16x16x32_bf16(af[mi], bfr[ni],
                                                                          acc[mi][ni], 0, 0, 0);
        }
        __builtin_amdgcn_s_setprio(0);
        __syncthreads();                          // all reads done before next issue
    }
    // QK done. S in acc: local row = wm0 + mi*16 + quad*4 + r, local col = wn0 + ni*16 + l15.

    // scale + causal mask (only tiles straddling the diagonal: bx >= 2*by)
    const bool diag = (bx >= 2 * by);
    #pragma unroll
    for (int mi = 0; mi < 4; ++mi)
        #pragma unroll
        for (int ni = 0; ni < 4; ++ni)
            #pragma unroll
            for (int r = 0; r < 4; ++r) {
                float v = acc[mi][ni][r] * SCALE;
                if (diag) {
                    int grow = (int)m0 + wm0 + mi * 16 + quad * 4 + r;
                    int gcol = (int)n0 + wn0 + ni * 16 + l15;
                    if (gcol > grow) v = -INFINITY;
                }
                acc[mi][ni][r] = v;
            }

    // row max within tile (row = wm0 + mi*16 + quad*4 + r; two col-waves per row)
    float rmax[4][4];
    #pragma unroll
    for (int mi = 0; mi < 4; ++mi)
        #pragma unroll
        for (int r = 0; r < 4; ++r) {
            float m = fmaxf(fmaxf(acc[mi][0][r], acc[mi][1][r]),
                            fmaxf(acc[mi][2][r], acc[mi][3][r]));
            #pragma unroll
            for (int msk = 8; msk >= 1; msk >>= 1) m = fmaxf(m, __shfl_xor(m, msk));
            rmax[mi][r] = m;
            if (l15 == 0) smax[(wm0 + mi * 16 + quad * 4 + r) * 2 + (wave & 1)] = m;
        }
    __syncthreads();
    #pragma unroll
    for (int mi = 0; mi < 4; ++mi)
        #pragma unroll
        for (int r = 0; r < 4; ++r) {
            int row = wm0 + mi * 16 + quad * 4 + r;
            rmax[mi][r] = fmaxf(smax[row * 2], smax[row * 2 + 1]);
        }

    // exp + row sums
    #pragma unroll
    for (int mi = 0; mi < 4; ++mi)
        #pragma unroll
        for (int r = 0; r < 4; ++r) {
            float s = 0.f;
            #pragma unroll
            for (int ni = 0; ni < 4; ++ni) {
                float p = __expf(acc[mi][ni][r] - rmax[mi][r]);
                acc[mi][ni][r] = p;
                s += p;
            }
            #pragma unroll
            for (int msk = 8; msk >= 1; msk >>= 1) s += __shfl_xor(s, msk);
            if (l15 == 0) ssum[(wm0 + mi * 16 + quad * 4 + r) * 2 + (wave & 1)] = s;
        }

    // half 0: even waves (wn0==0) write P~ cols 0..63 into Ps[256][66]
    if ((wave & 1) == 0) {
        #pragma unroll
        for (int mi = 0; mi < 4; ++mi) {
            int row = wm0 + mi * 16 + quad * 4;
            #pragma unroll
            for (int ni = 0; ni < 4; ++ni) {
                int col = ni * 16 + l15;
                #pragma unroll
                for (int r = 0; r < 4; ++r)
                    Ps[(row + r) * 66 + col] =
                        (unsigned short)__bfloat16_as_ushort(__float2bfloat16(acc[mi][ni][r]));
            }
        }
    }
    // write prefetched V chunk: Vs[j][k], xor-swizzled 16B chunks
    #pragma unroll
    for (int p = 0; p < 2; ++p) {
        int j = (tid >> 4) + p * 32;
        int ch = tid & 15;
        *reinterpret_cast<uint4*>(&Vs[j * 136 + ((ch ^ (j & 7)) * 8)]) = vreg[p];
    }
    __syncthreads();

    // per-row stats out (m, l) for 256 rows
    if (tid < 256) {
        float m = fmaxf(smax[tid * 2], smax[tid * 2 + 1]);
        float l = ssum[tid * 2] + ssum[tid * 2 + 1];
        long long o = (((long long)b * 16 + bx) * SS + m0 + tid) * 2;
        stats[o] = m;
        stats[o + 1] = l;
    }

    // O' = P~ . V  (M=256, N=64, K=128) in two K-halves, chunk order 0,1,2,3
    const int wmv = wave * 32;                   // each wave owns 32 output rows
    floatx4 accO[2][4] = {};
    __builtin_amdgcn_s_setprio(1);
    #pragma unroll
    for (int sk = 0; sk < 2; ++sk) {                       // half 0: kc = sk
        #pragma unroll
        for (int mi = 0; mi < 2; ++mi) {
            bf16x8 af = *reinterpret_cast<const bf16x8*>(
                &Ps[(wmv + mi * 16 + l15) * 66 + sk * 32 + quad * 8]);
            #pragma unroll
            for (int ni = 0; ni < 4; ++ni) {
                bf16x8 bfv = *reinterpret_cast<const bf16x8*>(
                    &Vs[(ni * 16 + l15) * 136 + (((sk << 2) | quad) ^ sw7) * 8]);
                accO[mi][ni] = __builtin_amdgcn_mfma_f32_16x16x32_bf16(af, bfv, accO[mi][ni], 0, 0, 0);
            }
        }
    }
    __builtin_amdgcn_s_setprio(0);
    __syncthreads();

    // half 1: odd waves (wn0==64) write P~ cols 64..127
    if ((wave & 1) == 1) {
        #pragma unroll
        for (int mi = 0; mi < 4; ++mi) {
            int row = wm0 + mi * 16 + quad * 4;
            #pragma unroll
            for (int ni = 0; ni < 4; ++ni) {
                int col = ni * 16 + l15;
                #pragma unroll
                for (int r = 0; r < 4; ++r)
                    Ps[(row + r) * 66 + col] =
                        (unsigned short)__bfloat16_as_ushort(__float2bfloat16(acc[mi][ni][r]));
            }
        }
    }
    __syncthreads();

    __builtin_amdgcn_s_setprio(1);
    #pragma unroll
    for (int sk = 0; sk < 2; ++sk) {                       // half 1: kc = 2 + sk
        const int kc = 2 + sk;
        #pragma unroll
        for (int mi = 0; mi < 2; ++mi) {
            bf16x8 af = *reinterpret_cast<const bf16x8*>(
                &Ps[(wmv + mi * 16 + l15) * 66 + sk * 32 + quad * 8]);
            #pragma unroll
            for (int ni = 0; ni < 4; ++ni) {
                bf16x8 bfv = *reinterpret_cast<const bf16x8*>(
                    &Vs[(ni * 16 + l15) * 136 + (((kc << 2) | quad) ^ sw7) * 8]);
                accO[mi][ni] = __builtin_amdgcn_mfma_f32_16x16x32_bf16(af, bfv, accO[mi][ni], 0, 0, 0);
            }
        }
    }
    __builtin_amdgcn_s_setprio(0);

    #pragma unroll
    for (int mi = 0; mi < 2; ++mi)
        #pragma unroll
        for (int ni = 0; ni < 4; ++ni)
            #pragma unroll
            for (int r = 0; r < 4; ++r)
                part[(((long long)b * 16 + bx) * SS + m0 + wmv + mi * 16 + quad * 4 + r) * 64
                     + ni * 16 + l15] = __float2bfloat16(accO[mi][ni][r]);
}

// ---------------- combine k-tile partials (vectorized x8 bf16 loads) ----------------
__global__ __launch_bounds__(256) void combine(const bf16* __restrict__ part,
                                               const float* __restrict__ stats,
                                               float* __restrict__ out) {
    int tid = blockIdx.x * 256 + threadIdx.x;   // over 8192*8
    int row = tid >> 3;
    int col8 = (tid & 7) * 8;
    int b = row >> 11, s = row & (SS - 1);
    int nt = (s >> 7) + 1;                      // live k-tiles for this row

    float m[16], l[16], M = -INFINITY;
    #pragma unroll
    for (int t = 0; t < 16; ++t)
        if (t < nt) {
            long long o = (((long long)b * 16 + t) * SS + s) * 2;
            m[t] = stats[o];
            l[t] = stats[o + 1];
            M = fmaxf(M, m[t]);
        }
    float O[8] = {};
    float L = 0.f;
    #pragma unroll
    for (int t = 0; t < 16; ++t)
        if (t < nt) {
            float wgt = __expf(m[t] - M);
            L += wgt * l[t];
            union { uint4 q; unsigned short u[8]; } ld;
            ld.q = *reinterpret_cast<const uint4*>(
                part + (((long long)b * 16 + t) * SS + s) * 64 + col8);
            #pragma unroll
            for (int j = 0; j < 8; ++j)
                O[j] += wgt * __uint_as_float((unsigned)ld.u[j] << 16);
        }
    float rinv = 1.0f / L;
    float4 o0 = {O[0] * rinv, O[1] * rinv, O[2] * rinv, O[3] * rinv};
    float4 o1 = {O[4] * rinv, O[5] * rinv, O[6] * rinv, O[7] * rinv};
    float4* dst = reinterpret_cast<float4*>(out + (long long)row * 64 + col8);
    dst[0] = o0;
    dst[1] = o1;
}

extern "C" void kernel_launch(void* const* d_in, const int* in_sizes, int n_in,
                              void* d_out, int out_size, void* d_ws, size_t ws_size,
                              hipStream_t stream) {
    const float* x  = (const float*)d_in[0];
    const float* Wq = (const float*)d_in[1];
    const float* Wk = (const float*)d_in[2];
    const float* Wv = (const float*)d_in[3];
    float* out = (float*)d_out;

    char* w = (char*)d_ws;
    bf16* xb   = (bf16*)(w + XB_OFF);
    bf16* wqb  = (bf16*)(w + WQB_OFF);
    bf16* wkb  = (bf16*)(w + WKB_OFF);
    bf16* wt2  = (bf16*)(w + WT2_OFF);
    float* mtp = (float*)(w + MTP_OFF);
    bf16* yv   = (bf16*)(w + YV_OFF);
    bf16* vt   = (bf16*)(w + VT_OFF);
    bf16* part = (bf16*)(w + PRT_OFF);
    float* stats = (float*)(w + STA_OFF);

    // 1. fused prep: x->xb, Wq/Wk->bf16, Wv->wt2 rows 512..575 (transposed)
    prep<<<6176, 256, 0, stream>>>(x, Wq, Wk, Wv, xb, wqb, wkb, wt2);

    // 2. Mt = Wk·Wq^T [512x512] (split-K 8 partials + reduce) -> wt2 rows 0..511
    gemm_mt<<<128, 256, 0, stream>>>(wkb, wqb, mtp);
    reduce_mt<<<65536 / 256, 256, 0, stream>>>((const float4*)mtp, wt2);

    // 3. yv = xb·wt2^T (y cols) + vt written transposed directly from the v N-tile
    gemm_proj<<<320, 256, 0, stream>>>(xb, wt2, yv, vt);

    // 4. fused attention tiles: M=256 x N=128, scores = y·x^T (K=512), softmax, P~V
    attn_fused<<<dim3(72, 1, BB), 512, 0, stream>>>(yv, xb, vt, part, stats);

    // 5. combine partials -> out
    combine<<<ROWS * 8 / 256, 256, 0, stream>>>(part, stats, out);
}

// Round 5
// 144.645 us; speedup vs baseline: 1.1825x; 1.1825x over previous
//
#include <hip/hip_runtime.h>
#include <hip/hip_bf16.h>
#include <math.h>

using bf16 = __hip_bfloat16;
typedef __bf16 bf16x8 __attribute__((ext_vector_type(8)));
typedef float floatx4 __attribute__((ext_vector_type(4)));

// Problem dims
constexpr int BB = 4, SS = 2048, DIN = 512, DKK = 2048, DVV = 64;
constexpr int ROWS = BB * SS;          // 8192
constexpr int LDY = 640;               // yv row: y(512) | pad(128, garbage ok)

// ---- workspace layout (bytes) ----
constexpr size_t XB_OFF  = 0;                          // bf16 xb  [8192][512]   (8 MB)
constexpr size_t WQB_OFF = XB_OFF  + 8388608;          // bf16 wqb [512][2048]   (2 MB)
constexpr size_t WKB_OFF = WQB_OFF + 2097152;          // bf16 wkb [512][2048]   (2 MB)
constexpr size_t WT2_OFF = WKB_OFF + 2097152;          // bf16 wt2 [640][512]
constexpr size_t MTP_OFF = WT2_OFF + 655360;           // fp32 mt partials [8][512][512] (8 MB)
constexpr size_t YV_OFF  = MTP_OFF + 8388608;          // bf16 yv  [8192][640]   (10 MB)
constexpr size_t VT_OFF  = YV_OFF  + 10485760;         // bf16 vt  [4][64][2048] (1 MB)
constexpr size_t PRT_OFF = VT_OFF  + 1048576;          // bf16 O' partials [4][16][2048][64] (16 MB)
constexpr size_t STA_OFF = PRT_OFF + 16777216;         // fp32 stats [4][16][2048][2] (1 MB)

__device__ __forceinline__ void async_copy16(const bf16* g, const unsigned short* l) {
    __builtin_amdgcn_global_load_lds((const __attribute__((address_space(1))) void*)g,
                                     (__attribute__((address_space(3))) void*)l, 16, 0, 0);
}

// ---------------- fused prep: convert x | convert Wq,Wk | transpose Wv ----------------
__global__ __launch_bounds__(256) void prep(const float* __restrict__ x,
                                            const float* __restrict__ Wq,
                                            const float* __restrict__ Wk,
                                            const float* __restrict__ Wv,
                                            bf16* __restrict__ xb,
                                            bf16* __restrict__ wqb,
                                            bf16* __restrict__ wkb,
                                            bf16* __restrict__ wt2) {
    __shared__ float tile[32][33];
    const int bid = blockIdx.x;
    const int tid = threadIdx.x;

    if (bid < 4096) {
        int i = bid * 256 + tid;                     // over 1048576 float4 groups
        float4 v = reinterpret_cast<const float4*>(x)[i];
        union { bf16 h[4]; ushort4 u; } cv;
        cv.h[0] = __float2bfloat16(v.x);
        cv.h[1] = __float2bfloat16(v.y);
        cv.h[2] = __float2bfloat16(v.z);
        cv.h[3] = __float2bfloat16(v.w);
        reinterpret_cast<ushort4*>(xb)[i] = cv.u;
    } else if (bid < 6144) {
        int i = (bid - 4096) * 256 + tid;            // over 524288 float4 groups
        const float* src = (i < 262144) ? Wq : Wk;
        bf16* dst = (i < 262144) ? wqb : wkb;
        int j = (i < 262144) ? i : i - 262144;
        float4 v = reinterpret_cast<const float4*>(src)[j];
        union { bf16 h[4]; ushort4 u; } cv;
        cv.h[0] = __float2bfloat16(v.x);
        cv.h[1] = __float2bfloat16(v.y);
        cv.h[2] = __float2bfloat16(v.z);
        cv.h[3] = __float2bfloat16(v.w);
        reinterpret_cast<ushort4*>(dst)[j] = cv.u;
    } else {
        int idx = bid - 6144;                        // 0..31
        int n0 = (idx & 1) * 32;
        int k0 = (idx >> 1) * 32;
        int nn = tid & 31, kk8 = tid >> 5;
        #pragma unroll
        for (int p = 0; p < 4; ++p) {
            int k = p * 8 + kk8;
            tile[k][nn] = Wv[(long long)(k0 + k) * 64 + n0 + nn];
        }
        __syncthreads();
        int kk = tid & 31, nn8 = tid >> 5;
        #pragma unroll
        for (int p = 0; p < 4; ++p) {
            int n = p * 8 + nn8;
            wt2[(long long)(512 + n0 + n) * 512 + k0 + kk] = __float2bfloat16(tile[kk][n]);
        }
    }
}

// ---------------- Mt partial GEMM: Mt[j][i] = sum_n wkb[j][n]*wqb[i][n], split-K 8 ----------------
__global__ __launch_bounds__(256) void gemm_mt(const bf16* __restrict__ A,
                                               const bf16* __restrict__ Bt,
                                               float* __restrict__ Cp) {
    __shared__ __align__(16) unsigned short As[128 * 64];
    __shared__ __align__(16) unsigned short Bs[128 * 64];

    const int tid = threadIdx.x;
    const int lane = tid & 63, wave = tid >> 6;

    // bijective XCD swizzle: 128 blocks, q = 16
    const int wg = (blockIdx.x & 7) * 16 + (blockIdx.x >> 3);
    const int z = wg >> 4;               // split-K plane 0..7
    const int tile = wg & 15;
    const long long m0 = (long long)(tile >> 2) * 128;
    const long long n0 = (long long)(tile & 3) * 128;
    const int koff = z * 256;

    const int rIn = lane >> 3;
    const int cSwz = ((lane & 7) ^ rIn) * 8;
    const int wm0 = (wave >> 1) * 64, wn0 = (wave & 1) * 64;
    const int l15 = lane & 15, quad = lane >> 4;
    const int sw7 = l15 & 7;

    floatx4 acc[4][4] = {};

    for (int k0 = koff; k0 < koff + 256; k0 += 64) {
        #pragma unroll
        for (int t0 = 0; t0 < 8; ++t0) {
            int t = t0 * 4 + wave;
            if (t < 16)
                async_copy16(A + (m0 + t * 8 + rIn) * 2048LL + k0 + cSwz, &As[t * 512]);
            else
                async_copy16(Bt + (n0 + (t - 16) * 8 + rIn) * 2048LL + k0 + cSwz, &Bs[(t - 16) * 512]);
        }
        __syncthreads();
        #pragma unroll
        for (int sk = 0; sk < 2; ++sk) {
            const int rchunk = (((sk << 2) | quad) ^ sw7) * 8;
            bf16x8 af[4], bfr[4];
            #pragma unroll
            for (int mi = 0; mi < 4; ++mi)
                af[mi] = *reinterpret_cast<const bf16x8*>(&As[(wm0 + mi * 16 + l15) * 64 + rchunk]);
            #pragma unroll
            for (int ni = 0; ni < 4; ++ni)
                bfr[ni] = *reinterpret_cast<const bf16x8*>(&Bs[(wn0 + ni * 16 + l15) * 64 + rchunk]);
            #pragma unroll
            for (int mi = 0; mi < 4; ++mi)
                #pragma unroll
                for (int ni = 0; ni < 4; ++ni)
                    acc[mi][ni] = __builtin_amdgcn_mfma_f32_16x16x32_bf16(af[mi], bfr[ni],
                                                                          acc[mi][ni], 0, 0, 0);
        }
        __syncthreads();
    }

    float* C = Cp + (long long)z * 262144;
    #pragma unroll
    for (int mi = 0; mi < 4; ++mi) {
        long long row0 = m0 + wm0 + mi * 16 + quad * 4;
        #pragma unroll
        for (int ni = 0; ni < 4; ++ni) {
            long long col = n0 + wn0 + ni * 16 + l15;
            #pragma unroll
            for (int r = 0; r < 4; ++r)
                C[(row0 + r) * 512 + col] = acc[mi][ni][r];
        }
    }
}

// ---------------- reduce Mt partials -> wt2 rows 0..511 (bf16) ----------------
__global__ __launch_bounds__(256) void reduce_mt(const float4* __restrict__ part,
                                                 bf16* __restrict__ wt2) {
    int i = blockIdx.x * 256 + threadIdx.x;          // over 65536 float4 groups
    float4 s = {0.f, 0.f, 0.f, 0.f};
    #pragma unroll
    for (int t = 0; t < 8; ++t) {
        float4 a = part[(long long)t * 65536 + i];
        s.x += a.x; s.y += a.y; s.z += a.z; s.w += a.w;
    }
    union { bf16 h[4]; ushort4 u; } cv;
    cv.h[0] = __float2bfloat16(s.x);
    cv.h[1] = __float2bfloat16(s.y);
    cv.h[2] = __float2bfloat16(s.z);
    cv.h[3] = __float2bfloat16(s.w);
    reinterpret_cast<ushort4*>(wt2)[i] = cv.u;
}

// ---------------- yv GEMM: yv[8192][0..512) = xb . wt2^T, K=512 ----------------
__global__ __launch_bounds__(256) void gemm_proj(const bf16* __restrict__ A,
                                                 const bf16* __restrict__ Bt,
                                                 bf16* __restrict__ C,
                                                 bf16* __restrict__ vt) {
    __shared__ __align__(16) unsigned short As[128 * 64];
    __shared__ __align__(16) unsigned short Bs[128 * 64];

    const int tid = threadIdx.x;
    const int lane = tid & 63, wave = tid >> 6;

    // bijective XCD swizzle: 320 blocks, q = 40; m-major enumeration
    const int wg = (blockIdx.x & 7) * 40 + (blockIdx.x >> 3);
    const long long m0 = (long long)(wg / 5) * 128;
    const long long n0 = (long long)(wg % 5) * 128;

    const int rIn = lane >> 3;
    const int cSwz = ((lane & 7) ^ rIn) * 8;
    const int wm0 = (wave >> 1) * 64, wn0 = (wave & 1) * 64;
    const int l15 = lane & 15, quad = lane >> 4;
    const int sw7 = l15 & 7;

    floatx4 acc[4][4] = {};

    for (int k0 = 0; k0 < DIN; k0 += 64) {
        #pragma unroll
        for (int t0 = 0; t0 < 8; ++t0) {
            int t = t0 * 4 + wave;
            if (t < 16)
                async_copy16(A + (m0 + t * 8 + rIn) * (long long)DIN + k0 + cSwz, &As[t * 512]);
            else
                async_copy16(Bt + (n0 + (t - 16) * 8 + rIn) * (long long)DIN + k0 + cSwz, &Bs[(t - 16) * 512]);
        }
        __syncthreads();
        #pragma unroll
        for (int sk = 0; sk < 2; ++sk) {
            const int rchunk = (((sk << 2) | quad) ^ sw7) * 8;
            bf16x8 af[4], bfr[4];
            #pragma unroll
            for (int mi = 0; mi < 4; ++mi)
                af[mi] = *reinterpret_cast<const bf16x8*>(&As[(wm0 + mi * 16 + l15) * 64 + rchunk]);
            #pragma unroll
            for (int ni = 0; ni < 4; ++ni)
                bfr[ni] = *reinterpret_cast<const bf16x8*>(&Bs[(wn0 + ni * 16 + l15) * 64 + rchunk]);
            #pragma unroll
            for (int mi = 0; mi < 4; ++mi)
                #pragma unroll
                for (int ni = 0; ni < 4; ++ni)
                    acc[mi][ni] = __builtin_amdgcn_mfma_f32_16x16x32_bf16(af[mi], bfr[ni],
                                                                          acc[mi][ni], 0, 0, 0);
        }
        __syncthreads();
    }

    if (n0 < 512) {
        // y columns -> yv (row stride LDY)
        #pragma unroll
        for (int mi = 0; mi < 4; ++mi) {
            long long row0 = m0 + wm0 + mi * 16 + quad * 4;
            #pragma unroll
            for (int ni = 0; ni < 4; ++ni) {
                long long col = n0 + wn0 + ni * 16 + l15;
                #pragma unroll
                for (int r = 0; r < 4; ++r)
                    C[(row0 + r) * (long long)LDY + col] = __float2bfloat16(acc[mi][ni][r]);
            }
        }
    } else if (!(wave & 1)) {
        // v columns (j = ni*16+l15 in [0,64)) -> vt[b][j][s] transposed
        const int b = (int)(m0 >> 11);
        const int sbase = ((int)m0 & 2047) + wm0;
        #pragma unroll
        for (int mi = 0; mi < 4; ++mi) {
            int s0 = sbase + mi * 16 + quad * 4;
            #pragma unroll
            for (int ni = 0; ni < 4; ++ni) {
                int j = ni * 16 + l15;
                union { bf16 h[4]; ushort4 u; } cv;
                #pragma unroll
                for (int r = 0; r < 4; ++r)
                    cv.h[r] = __float2bfloat16(acc[mi][ni][r]);
                *reinterpret_cast<ushort4*>(vt + ((long long)(b * DVV + j)) * SS + s0) = cv.u;
            }
        }
    }
}

// ---------------- fused causal attention tile (K=512: scores = y·x^T) ----------------
// M=128 x N=128, 544 blocks. QK stage double-buffered with COUNTED vmcnt (never 0 in
// main loop) + raw barriers: loads for iter it+2 stay in flight across iter it+1's MFMA.
// LDS 64 KB -> 2 blocks/CU (grid supplies 2.125). Softmax/PV identical to round-3.
__global__ __launch_bounds__(512) void attn_fused(const bf16* __restrict__ yv,
                                                  const bf16* __restrict__ xb,
                                                  const bf16* __restrict__ vt,
                                                  bf16* __restrict__ part,
                                                  float* __restrict__ stats) {
    constexpr int BK = 64;
    constexpr float SCALE = 0.022097086912079608f;   // 1/sqrt(2048)

    __shared__ __align__(16) char smem[65536];
    unsigned short* As = (unsigned short*)smem;             // [2][8192] QK A staging (32 KB)
    unsigned short* Bs = (unsigned short*)(smem + 32768);   // [2][8192] QK B staging (32 KB)
    unsigned short* Ps = (unsigned short*)smem;             // [128][72] P~ half (overlay, post-QK)
    unsigned short* Vs = (unsigned short*)(smem + 18432);   // [64][136] V chunk (overlay)
    float* smax = (float*)(smem + 35840);                   // [128][2]  (overlay)
    float* ssum = (float*)(smem + 36864);                   // [128][2]  (overlay)

    // XCD-aware causal tile decode (136 = 8 * 17, bijective)
    const int wg = (blockIdx.x & 7) * 17 + (blockIdx.x >> 3);
    int by = (int)((sqrtf(8.f * (float)wg + 1.f) - 1.f) * 0.5f);
    while ((by + 1) * (by + 2) / 2 <= wg) ++by;
    while (by * (by + 1) / 2 > wg) --by;
    const int bx = wg - by * (by + 1) / 2;
    const int b = blockIdx.z;

    const bf16* A  = yv + (long long)b * SS * LDY;           // y rows (q role)
    const bf16* Bt = xb + (long long)b * SS * 512;           // x rows (k role)

    const int tid = threadIdx.x;
    const int lane = tid & 63, wave = tid >> 6;
    const long long m0 = (long long)by * 128;
    const long long n0 = (long long)bx * 128;

    const int rIn = lane >> 3;
    const int cSwz = ((lane & 7) ^ rIn) * 8;
    const int wm0 = (wave >> 1) * 32, wn0 = (wave & 1) * 64;
    const int l15 = lane & 15, quad = lane >> 4;
    const int sw7 = l15 & 7;

    floatx4 acc[2][4] = {};

    // T14: prefetch V chunk to registers (ds_write after QK when Vs overlay is free)
    uint4 vreg[2];
    #pragma unroll
    for (int p = 0; p < 2; ++p) {
        int j = (tid >> 4) + p * 32;
        int ch = tid & 15;
        vreg[p] = *reinterpret_cast<const uint4*>(
            vt + ((long long)b * DVV + j) * SS + n0 + ch * 8);
    }

    auto issue = [&](int buf, int k0) {
        #pragma unroll
        for (int t0 = 0; t0 < 4; ++t0) {
            int t = t0 * 8 + wave;
            if (t < 16)
                async_copy16(A + (m0 + t * 8 + rIn) * (long long)LDY + k0 + cSwz,
                             &As[buf * 8192 + t * 512]);
            else
                async_copy16(Bt + (n0 + (t - 16) * 8 + rIn) * 512LL + k0 + cSwz,
                             &Bs[buf * 8192 + (t - 16) * 512]);
        }
    };

    // prologue: two buffers in flight (8 loads/thread outstanding)
    issue(0, 0);
    issue(1, BK);

    #pragma unroll
    for (int it = 0; it < DIN / BK; ++it) {      // 8 iterations (K=512)
        const int cur = it & 1;
        // wait for buf[cur] only: its 4 loads are never among the newest 4 outstanding
        if (it < DIN / BK - 1) asm volatile("s_waitcnt vmcnt(4)" ::: );
        else                   asm volatile("s_waitcnt vmcnt(0)" ::: );
        __builtin_amdgcn_sched_barrier(0);       // pin: no ds_read hoisted above the wait
        __builtin_amdgcn_s_barrier();
        __builtin_amdgcn_s_setprio(1);
        #pragma unroll
        for (int sk = 0; sk < 2; ++sk) {
            const int rchunk = ((sk << 2) | quad) ^ sw7;
            bf16x8 af[2], bfr[4];
            #pragma unroll
            for (int mi = 0; mi < 2; ++mi)
                af[mi] = *reinterpret_cast<const bf16x8*>(
                    &As[cur * 8192 + (wm0 + mi * 16 + l15) * BK + rchunk * 8]);
            #pragma unroll
            for (int ni = 0; ni < 4; ++ni)
                bfr[ni] = *reinterpret_cast<const bf16x8*>(
                    &Bs[cur * 8192 + (wn0 + ni * 16 + l15) * BK + rchunk * 8]);
            #pragma unroll
            for (int mi = 0; mi < 2; ++mi)
                #pragma unroll
                for (int ni = 0; ni < 4; ++ni)
                    acc[mi][ni] = __builtin_amdgcn_mfma_f32_16x16x32_bf16(af[mi], bfr[ni],
                                                                          acc[mi][ni], 0, 0, 0);
        }
        __builtin_amdgcn_s_setprio(0);
        __builtin_amdgcn_s_barrier();            // all reads of buf[cur] done
        __builtin_amdgcn_sched_barrier(0);       // pin: reissue stays below the barrier
        if (it + 2 < DIN / BK) issue(cur, (it + 2) * BK);
    }
    __syncthreads();                             // full fence before LDS overlay reuse
    // QK done. S in acc, C-layout: row=wm0+mi*16+quad*4+r, col=wn0+ni*16+l15.

    // scale + causal mask (diagonal tile only)
    #pragma unroll
    for (int mi = 0; mi < 2; ++mi)
        #pragma unroll
        for (int ni = 0; ni < 4; ++ni)
            #pragma unroll
            for (int r = 0; r < 4; ++r) {
                float v = acc[mi][ni][r] * SCALE;
                if (bx == by) {
                    int row = wm0 + mi * 16 + quad * 4 + r;
                    int col = wn0 + ni * 16 + l15;
                    if (col > row) v = -INFINITY;
                }
                acc[mi][ni][r] = v;
            }

    // row max within tile
    float rmax[2][4];
    #pragma unroll
    for (int mi = 0; mi < 2; ++mi)
        #pragma unroll
        for (int r = 0; r < 4; ++r) {
            float m = fmaxf(fmaxf(acc[mi][0][r], acc[mi][1][r]),
                            fmaxf(acc[mi][2][r], acc[mi][3][r]));
            #pragma unroll
            for (int msk = 8; msk >= 1; msk >>= 1) m = fmaxf(m, __shfl_xor(m, msk));
            rmax[mi][r] = m;
            if (l15 == 0) smax[(wm0 + mi * 16 + quad * 4 + r) * 2 + (wave & 1)] = m;
        }
    __syncthreads();
    #pragma unroll
    for (int mi = 0; mi < 2; ++mi)
        #pragma unroll
        for (int r = 0; r < 4; ++r) {
            int row = wm0 + mi * 16 + quad * 4 + r;
            rmax[mi][r] = fmaxf(smax[row * 2], smax[row * 2 + 1]);
        }

    // exp + row sums
    #pragma unroll
    for (int mi = 0; mi < 2; ++mi)
        #pragma unroll
        for (int r = 0; r < 4; ++r) {
            float s = 0.f;
            #pragma unroll
            for (int ni = 0; ni < 4; ++ni) {
                float p = __expf(acc[mi][ni][r] - rmax[mi][r]);
                acc[mi][ni][r] = p;
                s += p;
            }
            #pragma unroll
            for (int msk = 8; msk >= 1; msk >>= 1) s += __shfl_xor(s, msk);
            if (l15 == 0) ssum[(wm0 + mi * 16 + quad * 4 + r) * 2 + (wave & 1)] = s;
        }

    // half 0: even waves (wn0==0) write P~ cols 0..63 into Ps[128][72]
    if ((wave & 1) == 0) {
        #pragma unroll
        for (int mi = 0; mi < 2; ++mi) {
            int row = wm0 + mi * 16 + quad * 4;
            #pragma unroll
            for (int ni = 0; ni < 4; ++ni) {
                int col = ni * 16 + l15;
                #pragma unroll
                for (int r = 0; r < 4; ++r)
                    Ps[(row + r) * 72 + col] =
                        (unsigned short)__bfloat16_as_ushort(__float2bfloat16(acc[mi][ni][r]));
            }
        }
    }
    // write prefetched V chunk: Vs[j][k], xor-swizzled 16B chunks
    #pragma unroll
    for (int p = 0; p < 2; ++p) {
        int j = (tid >> 4) + p * 32;
        int ch = tid & 15;
        *reinterpret_cast<uint4*>(&Vs[j * 136 + ((ch ^ (j & 7)) * 8)]) = vreg[p];
    }
    __syncthreads();

    // per-row stats out (m, l)
    if (tid < 128) {
        float m = fmaxf(smax[tid * 2], smax[tid * 2 + 1]);
        float l = ssum[tid * 2] + ssum[tid * 2 + 1];
        long long o = (((long long)b * 16 + bx) * SS + m0 + tid) * 2;
        stats[o] = m;
        stats[o + 1] = l;
    }

    // O' = P~ . V  in two K-halves (k-chunk order 0,1,2,3 == monolithic version)
    const int wmv = wave * 16;
    floatx4 accO[4] = {};
    __builtin_amdgcn_s_setprio(1);
    #pragma unroll
    for (int sk = 0; sk < 2; ++sk) {                       // half 0: kc = sk
        bf16x8 af = *reinterpret_cast<const bf16x8*>(
            &Ps[(wmv + l15) * 72 + sk * 32 + quad * 8]);
        #pragma unroll
        for (int ni = 0; ni < 4; ++ni) {
            bf16x8 bfv = *reinterpret_cast<const bf16x8*>(
                &Vs[(ni * 16 + l15) * 136 + (((sk << 2) | quad) ^ sw7) * 8]);
            accO[ni] = __builtin_amdgcn_mfma_f32_16x16x32_bf16(af, bfv, accO[ni], 0, 0, 0);
        }
    }
    __builtin_amdgcn_s_setprio(0);
    __syncthreads();

    // half 1: odd waves (wn0==64) write P~ cols 64..127
    if ((wave & 1) == 1) {
        #pragma unroll
        for (int mi = 0; mi < 2; ++mi) {
            int row = wm0 + mi * 16 + quad * 4;
            #pragma unroll
            for (int ni = 0; ni < 4; ++ni) {
                int col = ni * 16 + l15;
                #pragma unroll
                for (int r = 0; r < 4; ++r)
                    Ps[(row + r) * 72 + col] =
                        (unsigned short)__bfloat16_as_ushort(__float2bfloat16(acc[mi][ni][r]));
            }
        }
    }
    __syncthreads();

    __builtin_amdgcn_s_setprio(1);
    #pragma unroll
    for (int sk = 0; sk < 2; ++sk) {                       // half 1: kc = 2 + sk
        const int kc = 2 + sk;
        bf16x8 af = *reinterpret_cast<const bf16x8*>(
            &Ps[(wmv + l15) * 72 + sk * 32 + quad * 8]);
        #pragma unroll
        for (int ni = 0; ni < 4; ++ni) {
            bf16x8 bfv = *reinterpret_cast<const bf16x8*>(
                &Vs[(ni * 16 + l15) * 136 + (((kc << 2) | quad) ^ sw7) * 8]);
            accO[ni] = __builtin_amdgcn_mfma_f32_16x16x32_bf16(af, bfv, accO[ni], 0, 0, 0);
        }
    }
    __builtin_amdgcn_s_setprio(0);

    #pragma unroll
    for (int ni = 0; ni < 4; ++ni)
        #pragma unroll
        for (int r = 0; r < 4; ++r)
            part[(((long long)b * 16 + bx) * SS + m0 + wmv + quad * 4 + r) * 64 + ni * 16 + l15]
                = __float2bfloat16(accO[ni][r]);
}

// ---------------- combine k-tile partials (vectorized x8 bf16 loads) ----------------
__global__ __launch_bounds__(256) void combine(const bf16* __restrict__ part,
                                               const float* __restrict__ stats,
                                               float* __restrict__ out) {
    int tid = blockIdx.x * 256 + threadIdx.x;   // over 8192*8
    int row = tid >> 3;
    int col8 = (tid & 7) * 8;
    int b = row >> 11, s = row & (SS - 1);
    int nt = (s >> 7) + 1;                      // live k-tiles for this row

    float m[16], l[16], M = -INFINITY;
    #pragma unroll
    for (int t = 0; t < 16; ++t)
        if (t < nt) {
            long long o = (((long long)b * 16 + t) * SS + s) * 2;
            m[t] = stats[o];
            l[t] = stats[o + 1];
            M = fmaxf(M, m[t]);
        }
    float O[8] = {};
    float L = 0.f;
    #pragma unroll
    for (int t = 0; t < 16; ++t)
        if (t < nt) {
            float wgt = __expf(m[t] - M);
            L += wgt * l[t];
            union { uint4 q; unsigned short u[8]; } ld;
            ld.q = *reinterpret_cast<const uint4*>(
                part + (((long long)b * 16 + t) * SS + s) * 64 + col8);
            #pragma unroll
            for (int j = 0; j < 8; ++j)
                O[j] += wgt * __uint_as_float((unsigned)ld.u[j] << 16);
        }
    float rinv = 1.0f / L;
    float4 o0 = {O[0] * rinv, O[1] * rinv, O[2] * rinv, O[3] * rinv};
    float4 o1 = {O[4] * rinv, O[5] * rinv, O[6] * rinv, O[7] * rinv};
    float4* dst = reinterpret_cast<float4*>(out + (long long)row * 64 + col8);
    dst[0] = o0;
    dst[1] = o1;
}

extern "C" void kernel_launch(void* const* d_in, const int* in_sizes, int n_in,
                              void* d_out, int out_size, void* d_ws, size_t ws_size,
                              hipStream_t stream) {
    const float* x  = (const float*)d_in[0];
    const float* Wq = (const float*)d_in[1];
    const float* Wk = (const float*)d_in[2];
    const float* Wv = (const float*)d_in[3];
    float* out = (float*)d_out;

    char* w = (char*)d_ws;
    bf16* xb   = (bf16*)(w + XB_OFF);
    bf16* wqb  = (bf16*)(w + WQB_OFF);
    bf16* wkb  = (bf16*)(w + WKB_OFF);
    bf16* wt2  = (bf16*)(w + WT2_OFF);
    float* mtp = (float*)(w + MTP_OFF);
    bf16* yv   = (bf16*)(w + YV_OFF);
    bf16* vt   = (bf16*)(w + VT_OFF);
    bf16* part = (bf16*)(w + PRT_OFF);
    float* stats = (float*)(w + STA_OFF);

    // 1. fused prep: x->xb, Wq/Wk->bf16, Wv->wt2 rows 512..575 (transposed)
    prep<<<6176, 256, 0, stream>>>(x, Wq, Wk, Wv, xb, wqb, wkb, wt2);

    // 2. Mt = Wk·Wq^T [512x512] (split-K 8 partials + reduce) -> wt2 rows 0..511
    gemm_mt<<<128, 256, 0, stream>>>(wkb, wqb, mtp);
    reduce_mt<<<65536 / 256, 256, 0, stream>>>((const float4*)mtp, wt2);

    // 3. yv = xb·wt2^T (y cols) + vt written transposed directly from the v N-tile
    gemm_proj<<<320, 256, 0, stream>>>(xb, wt2, yv, vt);

    // 4. fused attention tiles: scores = y·x^T (K=512), softmax, P~V
    attn_fused<<<dim3(136, 1, BB), 512, 0, stream>>>(yv, xb, vt, part, stats);

    // 5. combine partials -> out
    combine<<<ROWS * 8 / 256, 256, 0, stream>>>(part, stats, out);
}

// Round 6
// 140.403 us; speedup vs baseline: 1.2182x; 1.0302x over previous
//
#include <hip/hip_runtime.h>
#include <hip/hip_bf16.h>
#include <math.h>

using bf16 = __hip_bfloat16;
typedef __bf16 bf16x8 __attribute__((ext_vector_type(8)));
typedef float floatx4 __attribute__((ext_vector_type(4)));

// Problem dims
constexpr int BB = 4, SS = 2048, DIN = 512, DKK = 2048, DVV = 64;
constexpr int ROWS = BB * SS;          // 8192
constexpr int LDY = 640;               // yv row: y(512) | pad(128, garbage ok)

// ---- workspace layout (bytes) ----
constexpr size_t XB_OFF  = 0;                          // bf16 xb  [8192][512]   (8 MB)
constexpr size_t WQB_OFF = XB_OFF  + 8388608;          // bf16 wqb [512][2048]   (2 MB)
constexpr size_t WKB_OFF = WQB_OFF + 2097152;          // bf16 wkb [512][2048]   (2 MB)
constexpr size_t WT2_OFF = WKB_OFF + 2097152;          // bf16 wt2 [640][512]
constexpr size_t MTP_OFF = WT2_OFF + 655360;           // fp32 mt partials [8][512][512] (8 MB)
constexpr size_t YV_OFF  = MTP_OFF + 8388608;          // bf16 yv  [8192][640]   (10 MB)
constexpr size_t VT_OFF  = YV_OFF  + 10485760;         // bf16 vt  [4][64][2048] (1 MB)
constexpr size_t PRT_OFF = VT_OFF  + 1048576;          // bf16 O' partials [4][16][2048][64] (16 MB)
constexpr size_t STA_OFF = PRT_OFF + 16777216;         // fp32 stats [4][16][2048][2] (1 MB)

__device__ __forceinline__ void async_copy16(const bf16* g, const unsigned short* l) {
    __builtin_amdgcn_global_load_lds((const __attribute__((address_space(1))) void*)g,
                                     (__attribute__((address_space(3))) void*)l, 16, 0, 0);
}

// ---------------- fused prep: convert x | convert Wq,Wk | transpose Wv ----------------
__global__ __launch_bounds__(256) void prep(const float* __restrict__ x,
                                            const float* __restrict__ Wq,
                                            const float* __restrict__ Wk,
                                            const float* __restrict__ Wv,
                                            bf16* __restrict__ xb,
                                            bf16* __restrict__ wqb,
                                            bf16* __restrict__ wkb,
                                            bf16* __restrict__ wt2) {
    __shared__ float tile[32][33];
    const int bid = blockIdx.x;
    const int tid = threadIdx.x;

    if (bid < 4096) {
        int i = bid * 256 + tid;                     // over 1048576 float4 groups
        float4 v = reinterpret_cast<const float4*>(x)[i];
        union { bf16 h[4]; ushort4 u; } cv;
        cv.h[0] = __float2bfloat16(v.x);
        cv.h[1] = __float2bfloat16(v.y);
        cv.h[2] = __float2bfloat16(v.z);
        cv.h[3] = __float2bfloat16(v.w);
        reinterpret_cast<ushort4*>(xb)[i] = cv.u;
    } else if (bid < 6144) {
        int i = (bid - 4096) * 256 + tid;            // over 524288 float4 groups
        const float* src = (i < 262144) ? Wq : Wk;
        bf16* dst = (i < 262144) ? wqb : wkb;
        int j = (i < 262144) ? i : i - 262144;
        float4 v = reinterpret_cast<const float4*>(src)[j];
        union { bf16 h[4]; ushort4 u; } cv;
        cv.h[0] = __float2bfloat16(v.x);
        cv.h[1] = __float2bfloat16(v.y);
        cv.h[2] = __float2bfloat16(v.z);
        cv.h[3] = __float2bfloat16(v.w);
        reinterpret_cast<ushort4*>(dst)[j] = cv.u;
    } else {
        int idx = bid - 6144;                        // 0..31
        int n0 = (idx & 1) * 32;
        int k0 = (idx >> 1) * 32;
        int nn = tid & 31, kk8 = tid >> 5;
        #pragma unroll
        for (int p = 0; p < 4; ++p) {
            int k = p * 8 + kk8;
            tile[k][nn] = Wv[(long long)(k0 + k) * 64 + n0 + nn];
        }
        __syncthreads();
        int kk = tid & 31, nn8 = tid >> 5;
        #pragma unroll
        for (int p = 0; p < 4; ++p) {
            int n = p * 8 + nn8;
            wt2[(long long)(512 + n0 + n) * 512 + k0 + kk] = __float2bfloat16(tile[kk][n]);
        }
    }
}

// ---------------- Mt partial GEMM: Mt[j][i] = sum_n wkb[j][n]*wqb[i][n], split-K 8 ----------------
__global__ __launch_bounds__(256) void gemm_mt(const bf16* __restrict__ A,
                                               const bf16* __restrict__ Bt,
                                               float* __restrict__ Cp) {
    __shared__ __align__(16) unsigned short As[128 * 64];
    __shared__ __align__(16) unsigned short Bs[128 * 64];

    const int tid = threadIdx.x;
    const int lane = tid & 63, wave = tid >> 6;

    // bijective XCD swizzle: 128 blocks, q = 16
    const int wg = (blockIdx.x & 7) * 16 + (blockIdx.x >> 3);
    const int z = wg >> 4;               // split-K plane 0..7
    const int tile = wg & 15;
    const long long m0 = (long long)(tile >> 2) * 128;
    const long long n0 = (long long)(tile & 3) * 128;
    const int koff = z * 256;

    const int rIn = lane >> 3;
    const int cSwz = ((lane & 7) ^ rIn) * 8;
    const int wm0 = (wave >> 1) * 64, wn0 = (wave & 1) * 64;
    const int l15 = lane & 15, quad = lane >> 4;
    const int sw7 = l15 & 7;

    floatx4 acc[4][4] = {};

    for (int k0 = koff; k0 < koff + 256; k0 += 64) {
        #pragma unroll
        for (int t0 = 0; t0 < 8; ++t0) {
            int t = t0 * 4 + wave;
            if (t < 16)
                async_copy16(A + (m0 + t * 8 + rIn) * 2048LL + k0 + cSwz, &As[t * 512]);
            else
                async_copy16(Bt + (n0 + (t - 16) * 8 + rIn) * 2048LL + k0 + cSwz, &Bs[(t - 16) * 512]);
        }
        __syncthreads();
        #pragma unroll
        for (int sk = 0; sk < 2; ++sk) {
            const int rchunk = (((sk << 2) | quad) ^ sw7) * 8;
            bf16x8 af[4], bfr[4];
            #pragma unroll
            for (int mi = 0; mi < 4; ++mi)
                af[mi] = *reinterpret_cast<const bf16x8*>(&As[(wm0 + mi * 16 + l15) * 64 + rchunk]);
            #pragma unroll
            for (int ni = 0; ni < 4; ++ni)
                bfr[ni] = *reinterpret_cast<const bf16x8*>(&Bs[(wn0 + ni * 16 + l15) * 64 + rchunk]);
            #pragma unroll
            for (int mi = 0; mi < 4; ++mi)
                #pragma unroll
                for (int ni = 0; ni < 4; ++ni)
                    acc[mi][ni] = __builtin_amdgcn_mfma_f32_16x16x32_bf16(af[mi], bfr[ni],
                                                                          acc[mi][ni], 0, 0, 0);
        }
        __syncthreads();
    }

    float* C = Cp + (long long)z * 262144;
    #pragma unroll
    for (int mi = 0; mi < 4; ++mi) {
        long long row0 = m0 + wm0 + mi * 16 + quad * 4;
        #pragma unroll
        for (int ni = 0; ni < 4; ++ni) {
            long long col = n0 + wn0 + ni * 16 + l15;
            #pragma unroll
            for (int r = 0; r < 4; ++r)
                C[(row0 + r) * 512 + col] = acc[mi][ni][r];
        }
    }
}

// ---------------- reduce Mt partials -> wt2 rows 0..511 (bf16) ----------------
__global__ __launch_bounds__(256) void reduce_mt(const float4* __restrict__ part,
                                                 bf16* __restrict__ wt2) {
    int i = blockIdx.x * 256 + threadIdx.x;          // over 65536 float4 groups
    float4 s = {0.f, 0.f, 0.f, 0.f};
    #pragma unroll
    for (int t = 0; t < 8; ++t) {
        float4 a = part[(long long)t * 65536 + i];
        s.x += a.x; s.y += a.y; s.z += a.z; s.w += a.w;
    }
    union { bf16 h[4]; ushort4 u; } cv;
    cv.h[0] = __float2bfloat16(s.x);
    cv.h[1] = __float2bfloat16(s.y);
    cv.h[2] = __float2bfloat16(s.z);
    cv.h[3] = __float2bfloat16(s.w);
    reinterpret_cast<ushort4*>(wt2)[i] = cv.u;
}

// ---------------- yv GEMM: yv[8192][0..512) = xb . wt2^T, K=512 ----------------
__global__ __launch_bounds__(256) void gemm_proj(const bf16* __restrict__ A,
                                                 const bf16* __restrict__ Bt,
                                                 bf16* __restrict__ C,
                                                 bf16* __restrict__ vt) {
    __shared__ __align__(16) unsigned short As[128 * 64];
    __shared__ __align__(16) unsigned short Bs[128 * 64];

    const int tid = threadIdx.x;
    const int lane = tid & 63, wave = tid >> 6;

    // bijective XCD swizzle: 320 blocks, q = 40; m-major enumeration
    const int wg = (blockIdx.x & 7) * 40 + (blockIdx.x >> 3);
    const long long m0 = (long long)(wg / 5) * 128;
    const long long n0 = (long long)(wg % 5) * 128;

    const int rIn = lane >> 3;
    const int cSwz = ((lane & 7) ^ rIn) * 8;
    const int wm0 = (wave >> 1) * 64, wn0 = (wave & 1) * 64;
    const int l15 = lane & 15, quad = lane >> 4;
    const int sw7 = l15 & 7;

    floatx4 acc[4][4] = {};

    for (int k0 = 0; k0 < DIN; k0 += 64) {
        #pragma unroll
        for (int t0 = 0; t0 < 8; ++t0) {
            int t = t0 * 4 + wave;
            if (t < 16)
                async_copy16(A + (m0 + t * 8 + rIn) * (long long)DIN + k0 + cSwz, &As[t * 512]);
            else
                async_copy16(Bt + (n0 + (t - 16) * 8 + rIn) * (long long)DIN + k0 + cSwz, &Bs[(t - 16) * 512]);
        }
        __syncthreads();
        #pragma unroll
        for (int sk = 0; sk < 2; ++sk) {
            const int rchunk = (((sk << 2) | quad) ^ sw7) * 8;
            bf16x8 af[4], bfr[4];
            #pragma unroll
            for (int mi = 0; mi < 4; ++mi)
                af[mi] = *reinterpret_cast<const bf16x8*>(&As[(wm0 + mi * 16 + l15) * 64 + rchunk]);
            #pragma unroll
            for (int ni = 0; ni < 4; ++ni)
                bfr[ni] = *reinterpret_cast<const bf16x8*>(&Bs[(wn0 + ni * 16 + l15) * 64 + rchunk]);
            #pragma unroll
            for (int mi = 0; mi < 4; ++mi)
                #pragma unroll
                for (int ni = 0; ni < 4; ++ni)
                    acc[mi][ni] = __builtin_amdgcn_mfma_f32_16x16x32_bf16(af[mi], bfr[ni],
                                                                          acc[mi][ni], 0, 0, 0);
        }
        __syncthreads();
    }

    if (n0 < 512) {
        // y columns -> yv (row stride LDY)
        #pragma unroll
        for (int mi = 0; mi < 4; ++mi) {
            long long row0 = m0 + wm0 + mi * 16 + quad * 4;
            #pragma unroll
            for (int ni = 0; ni < 4; ++ni) {
                long long col = n0 + wn0 + ni * 16 + l15;
                #pragma unroll
                for (int r = 0; r < 4; ++r)
                    C[(row0 + r) * (long long)LDY + col] = __float2bfloat16(acc[mi][ni][r]);
            }
        }
    } else if (!(wave & 1)) {
        // v columns (j = ni*16+l15 in [0,64)) -> vt[b][j][s] transposed
        const int b = (int)(m0 >> 11);
        const int sbase = ((int)m0 & 2047) + wm0;
        #pragma unroll
        for (int mi = 0; mi < 4; ++mi) {
            int s0 = sbase + mi * 16 + quad * 4;
            #pragma unroll
            for (int ni = 0; ni < 4; ++ni) {
                int j = ni * 16 + l15;
                union { bf16 h[4]; ushort4 u; } cv;
                #pragma unroll
                for (int r = 0; r < 4; ++r)
                    cv.h[r] = __float2bfloat16(acc[mi][ni][r]);
                *reinterpret_cast<ushort4*>(vt + ((long long)(b * DVV + j)) * SS + s0) = cv.u;
            }
        }
    }
}

// ---------------- fused causal attention tile, M=64 x N=128, 4-wave blocks ----------------
// Concurrency-first: LDS 24576 B declared (+16K HW overhead = 40960) -> exactly 4 blocks/CU;
// grid 272 tiles/batch x 4 = 1088 blocks (4.25/CU available). Simple issue->sync->MFMA->sync
// loop (counted-vmcnt was null R5). PV in two sequential 64-col halves, V from registers;
// K-chunk order 0,1,2,3 preserved -> bit-identical numerics. stats/part layout unchanged.
__global__ __launch_bounds__(256) void attn_fused(const bf16* __restrict__ yv,
                                                  const bf16* __restrict__ xb,
                                                  const bf16* __restrict__ vt,
                                                  bf16* __restrict__ part,
                                                  float* __restrict__ stats) {
    constexpr int BK = 64;
    constexpr float SCALE = 0.022097086912079608f;   // 1/sqrt(2048)

    __shared__ __align__(16) char smem[24576];
    unsigned short* As = (unsigned short*)smem;             // [8*512]  QK A staging (8 KB, 64 rows)
    unsigned short* Bs = (unsigned short*)(smem + 8192);    // [16*512] QK B staging (16 KB, 128 rows)
    unsigned short* Ps = (unsigned short*)smem;             // [64][72] P~ half (overlay, post-QK)
    unsigned short* Vs = (unsigned short*)(smem + 9216);    // [64][72] V half (overlay)
    float* smax = (float*)(smem + 18432);                   // [64][2]
    float* ssum = (float*)(smem + 18944);                   // [64][2]

    // XCD swizzle (272 = 8*34, bijective) + causal half-tile decode:
    // by in [0,32) 64-row panels; bx in [0, by/2] 128-col k-tiles; C(by) = cumulative.
    const int wg = (blockIdx.x & 7) * 34 + (blockIdx.x >> 3);
    int by = 0, c = 0;
    while (c + (by >> 1) + 1 <= wg) { c += (by >> 1) + 1; ++by; }
    const int bx = wg - c;
    const int b = blockIdx.z;

    const bf16* A  = yv + (long long)b * SS * LDY;           // y rows (q role)
    const bf16* Bt = xb + (long long)b * SS * 512;           // x rows (k role)

    const int tid = threadIdx.x;
    const int lane = tid & 63, wave = tid >> 6;               // 4 waves
    const long long m0 = (long long)by * 64;
    const long long n0 = (long long)bx * 128;

    const int rIn = lane >> 3;
    const int cSwz = ((lane & 7) ^ rIn) * 8;
    const int wm0 = (wave >> 1) * 32, wn0 = (wave & 1) * 64;  // 2x2 waves over 64x128
    const int l15 = lane & 15, quad = lane >> 4;
    const int sw7 = l15 & 7;

    floatx4 acc[2][4] = {};

    // prefetch full V chunk V[64][n0..n0+128) to registers: 4 x uint4 per thread
    uint4 vreg[4];
    {
        int j = tid >> 2;
        int ch = tid & 3;
        #pragma unroll
        for (int p = 0; p < 4; ++p)
            vreg[p] = *reinterpret_cast<const uint4*>(
                vt + ((long long)b * DVV + j) * SS + n0 + (ch + p * 4) * 8);
    }

    auto issue = [&](int k0) {
        #pragma unroll
        for (int t0 = 0; t0 < 6; ++t0) {             // 24 slots: 8 A (64 rows) + 16 B (128 rows)
            int t = t0 * 4 + wave;
            if (t < 8)
                async_copy16(A + (m0 + t * 8 + rIn) * (long long)LDY + k0 + cSwz,
                             &As[t * 512]);
            else
                async_copy16(Bt + (n0 + (t - 8) * 8 + rIn) * 512LL + k0 + cSwz,
                             &Bs[(t - 8) * 512]);
        }
    };

    for (int it = 0; it < DIN / BK; ++it) {      // 8 iterations (K=512)
        issue(it * BK);
        __syncthreads();                          // loads landed
        __builtin_amdgcn_s_setprio(1);
        #pragma unroll
        for (int sk = 0; sk < 2; ++sk) {
            const int rchunk = (((sk << 2) | quad) ^ sw7) * 8;
            bf16x8 af[2], bfr[4];
            #pragma unroll
            for (int mi = 0; mi < 2; ++mi)
                af[mi] = *reinterpret_cast<const bf16x8*>(
                    &As[(wm0 + mi * 16 + l15) * BK + rchunk]);
            #pragma unroll
            for (int ni = 0; ni < 4; ++ni)
                bfr[ni] = *reinterpret_cast<const bf16x8*>(
                    &Bs[(wn0 + ni * 16 + l15) * BK + rchunk]);
            #pragma unroll
            for (int mi = 0; mi < 2; ++mi)
                #pragma unroll
                for (int ni = 0; ni < 4; ++ni)
                    acc[mi][ni] = __builtin_amdgcn_mfma_f32_16x16x32_bf16(af[mi], bfr[ni],
                                                                          acc[mi][ni], 0, 0, 0);
        }
        __builtin_amdgcn_s_setprio(0);
        __syncthreads();                          // all reads done before next issue
    }
    // QK done. S in acc: local row = wm0 + mi*16 + quad*4 + r, local col = wn0 + ni*16 + l15.

    // scale + causal mask (tiles straddling the diagonal: n0+127 > m0)
    const bool diag = (n0 + 127 > m0);
    #pragma unroll
    for (int mi = 0; mi < 2; ++mi)
        #pragma unroll
        for (int ni = 0; ni < 4; ++ni)
            #pragma unroll
            for (int r = 0; r < 4; ++r) {
                float v = acc[mi][ni][r] * SCALE;
                if (diag) {
                    int grow = (int)m0 + wm0 + mi * 16 + quad * 4 + r;
                    int gcol = (int)n0 + wn0 + ni * 16 + l15;
                    if (gcol > grow) v = -INFINITY;
                }
                acc[mi][ni][r] = v;
            }

    // row max within tile (2 col-waves per row)
    float rmax[2][4];
    #pragma unroll
    for (int mi = 0; mi < 2; ++mi)
        #pragma unroll
        for (int r = 0; r < 4; ++r) {
            float m = fmaxf(fmaxf(acc[mi][0][r], acc[mi][1][r]),
                            fmaxf(acc[mi][2][r], acc[mi][3][r]));
            #pragma unroll
            for (int msk = 8; msk >= 1; msk >>= 1) m = fmaxf(m, __shfl_xor(m, msk));
            rmax[mi][r] = m;
            if (l15 == 0) smax[(wm0 + mi * 16 + quad * 4 + r) * 2 + (wave & 1)] = m;
        }
    __syncthreads();
    #pragma unroll
    for (int mi = 0; mi < 2; ++mi)
        #pragma unroll
        for (int r = 0; r < 4; ++r) {
            int row = wm0 + mi * 16 + quad * 4 + r;
            rmax[mi][r] = fmaxf(smax[row * 2], smax[row * 2 + 1]);
        }

    // exp + row sums
    #pragma unroll
    for (int mi = 0; mi < 2; ++mi)
        #pragma unroll
        for (int r = 0; r < 4; ++r) {
            float s = 0.f;
            #pragma unroll
            for (int ni = 0; ni < 4; ++ni) {
                float p = __expf(acc[mi][ni][r] - rmax[mi][r]);
                acc[mi][ni][r] = p;
                s += p;
            }
            #pragma unroll
            for (int msk = 8; msk >= 1; msk >>= 1) s += __shfl_xor(s, msk);
            if (l15 == 0) ssum[(wm0 + mi * 16 + quad * 4 + r) * 2 + (wave & 1)] = s;
        }

    // half 0: even waves (wn0==0) write P~ cols 0..63 into Ps[64][72]
    if ((wave & 1) == 0) {
        #pragma unroll
        for (int mi = 0; mi < 2; ++mi) {
            int row = wm0 + mi * 16 + quad * 4;
            #pragma unroll
            for (int ni = 0; ni < 4; ++ni) {
                int col = ni * 16 + l15;
                #pragma unroll
                for (int r = 0; r < 4; ++r)
                    Ps[(row + r) * 72 + col] =
                        (unsigned short)__bfloat16_as_ushort(__float2bfloat16(acc[mi][ni][r]));
            }
        }
    }
    // write V half 0 (global chunks 0..7) xor-swizzled into Vs[64][72]
    {
        int j = tid >> 2;
        int ch = tid & 3;
        #pragma unroll
        for (int pp = 0; pp < 2; ++pp) {
            int chh = ch + pp * 4;                               // within-half chunk 0..7
            *reinterpret_cast<uint4*>(&Vs[j * 72 + ((chh ^ (j & 7)) * 8)]) = vreg[pp];
        }
    }
    __syncthreads();

    // per-row stats out (m, l) for 64 rows
    if (tid < 64) {
        float m = fmaxf(smax[tid * 2], smax[tid * 2 + 1]);
        float l = ssum[tid * 2] + ssum[tid * 2 + 1];
        long long o = (((long long)b * 16 + bx) * SS + m0 + tid) * 2;
        stats[o] = m;
        stats[o + 1] = l;
    }

    // O' = P~ . V  (M=64, N=64, K=128) in two halves; global k-chunk order 0,1,2,3
    const int wmv = wave * 16;
    floatx4 accO[4] = {};
    __builtin_amdgcn_s_setprio(1);
    #pragma unroll
    for (int sk = 0; sk < 2; ++sk) {                       // half 0: kc = sk
        bf16x8 af = *reinterpret_cast<const bf16x8*>(
            &Ps[(wmv + l15) * 72 + sk * 32 + quad * 8]);
        #pragma unroll
        for (int ni = 0; ni < 4; ++ni) {
            bf16x8 bfv = *reinterpret_cast<const bf16x8*>(
                &Vs[(ni * 16 + l15) * 72 + ((((sk << 2) | quad)) ^ sw7) * 8]);
            accO[ni] = __builtin_amdgcn_mfma_f32_16x16x32_bf16(af, bfv, accO[ni], 0, 0, 0);
        }
    }
    __builtin_amdgcn_s_setprio(0);
    __syncthreads();

    // half 1: odd waves (wn0==64) write P~ cols 64..127; V half 1 (chunks 8..15)
    if ((wave & 1) == 1) {
        #pragma unroll
        for (int mi = 0; mi < 2; ++mi) {
            int row = wm0 + mi * 16 + quad * 4;
            #pragma unroll
            for (int ni = 0; ni < 4; ++ni) {
                int col = ni * 16 + l15;
                #pragma unroll
                for (int r = 0; r < 4; ++r)
                    Ps[(row + r) * 72 + col] =
                        (unsigned short)__bfloat16_as_ushort(__float2bfloat16(acc[mi][ni][r]));
            }
        }
    }
    {
        int j = tid >> 2;
        int ch = tid & 3;
        #pragma unroll
        for (int pp = 0; pp < 2; ++pp) {
            int chh = ch + pp * 4;                               // within-half chunk 0..7
            *reinterpret_cast<uint4*>(&Vs[j * 72 + ((chh ^ (j & 7)) * 8)]) = vreg[2 + pp];
        }
    }
    __syncthreads();

    __builtin_amdgcn_s_setprio(1);
    #pragma unroll
    for (int sk = 0; sk < 2; ++sk) {                       // half 1: kc = 2 + sk
        bf16x8 af = *reinterpret_cast<const bf16x8*>(
            &Ps[(wmv + l15) * 72 + sk * 32 + quad * 8]);
        #pragma unroll
        for (int ni = 0; ni < 4; ++ni) {
            bf16x8 bfv = *reinterpret_cast<const bf16x8*>(
                &Vs[(ni * 16 + l15) * 72 + ((((sk << 2) | quad)) ^ sw7) * 8]);
            accO[ni] = __builtin_amdgcn_mfma_f32_16x16x32_bf16(af, bfv, accO[ni], 0, 0, 0);
        }
    }
    __builtin_amdgcn_s_setprio(0);

    #pragma unroll
    for (int ni = 0; ni < 4; ++ni)
        #pragma unroll
        for (int r = 0; r < 4; ++r)
            part[(((long long)b * 16 + bx) * SS + m0 + wmv + quad * 4 + r) * 64 + ni * 16 + l15]
                = __float2bfloat16(accO[ni][r]);
}

// ---------------- combine k-tile partials (vectorized x8 bf16 loads) ----------------
__global__ __launch_bounds__(256) void combine(const bf16* __restrict__ part,
                                               const float* __restrict__ stats,
                                               float* __restrict__ out) {
    int tid = blockIdx.x * 256 + threadIdx.x;   // over 8192*8
    int row = tid >> 3;
    int col8 = (tid & 7) * 8;
    int b = row >> 11, s = row & (SS - 1);
    int nt = (s >> 7) + 1;                      // live k-tiles for this row

    float m[16], l[16], M = -INFINITY;
    #pragma unroll
    for (int t = 0; t < 16; ++t)
        if (t < nt) {
            long long o = (((long long)b * 16 + t) * SS + s) * 2;
            m[t] = stats[o];
            l[t] = stats[o + 1];
            M = fmaxf(M, m[t]);
        }
    float O[8] = {};
    float L = 0.f;
    #pragma unroll
    for (int t = 0; t < 16; ++t)
        if (t < nt) {
            float wgt = __expf(m[t] - M);
            L += wgt * l[t];
            union { uint4 q; unsigned short u[8]; } ld;
            ld.q = *reinterpret_cast<const uint4*>(
                part + (((long long)b * 16 + t) * SS + s) * 64 + col8);
            #pragma unroll
            for (int j = 0; j < 8; ++j)
                O[j] += wgt * __uint_as_float((unsigned)ld.u[j] << 16);
        }
    float rinv = 1.0f / L;
    float4 o0 = {O[0] * rinv, O[1] * rinv, O[2] * rinv, O[3] * rinv};
    float4 o1 = {O[4] * rinv, O[5] * rinv, O[6] * rinv, O[7] * rinv};
    float4* dst = reinterpret_cast<float4*>(out + (long long)row * 64 + col8);
    dst[0] = o0;
    dst[1] = o1;
}

extern "C" void kernel_launch(void* const* d_in, const int* in_sizes, int n_in,
                              void* d_out, int out_size, void* d_ws, size_t ws_size,
                              hipStream_t stream) {
    const float* x  = (const float*)d_in[0];
    const float* Wq = (const float*)d_in[1];
    const float* Wk = (const float*)d_in[2];
    const float* Wv = (const float*)d_in[3];
    float* out = (float*)d_out;

    char* w = (char*)d_ws;
    bf16* xb   = (bf16*)(w + XB_OFF);
    bf16* wqb  = (bf16*)(w + WQB_OFF);
    bf16* wkb  = (bf16*)(w + WKB_OFF);
    bf16* wt2  = (bf16*)(w + WT2_OFF);
    float* mtp = (float*)(w + MTP_OFF);
    bf16* yv   = (bf16*)(w + YV_OFF);
    bf16* vt   = (bf16*)(w + VT_OFF);
    bf16* part = (bf16*)(w + PRT_OFF);
    float* stats = (float*)(w + STA_OFF);

    // 1. fused prep: x->xb, Wq/Wk->bf16, Wv->wt2 rows 512..575 (transposed)
    prep<<<6176, 256, 0, stream>>>(x, Wq, Wk, Wv, xb, wqb, wkb, wt2);

    // 2. Mt = Wk·Wq^T [512x512] (split-K 8 partials + reduce) -> wt2 rows 0..511
    gemm_mt<<<128, 256, 0, stream>>>(wkb, wqb, mtp);
    reduce_mt<<<65536 / 256, 256, 0, stream>>>((const float4*)mtp, wt2);

    // 3. yv = xb·wt2^T (y cols) + vt written transposed directly from the v N-tile
    gemm_proj<<<320, 256, 0, stream>>>(xb, wt2, yv, vt);

    // 4. fused attention: M=64 x N=128 4-wave tiles, 4 blocks/CU, grid 1088
    attn_fused<<<dim3(272, 1, BB), 256, 0, stream>>>(yv, xb, vt, part, stats);

    // 5. combine partials -> out
    combine<<<ROWS * 8 / 256, 256, 0, stream>>>(part, stats, out);
}

// Round 7
// 136.600 us; speedup vs baseline: 1.2522x; 1.0278x over previous
//
#include <hip/hip_runtime.h>
#include <hip/hip_bf16.h>
#include <math.h>

using bf16 = __hip_bfloat16;
typedef __bf16 bf16x8 __attribute__((ext_vector_type(8)));
typedef float floatx4 __attribute__((ext_vector_type(4)));

// Problem dims
constexpr int BB = 4, SS = 2048, DIN = 512, DKK = 2048, DVV = 64;
constexpr int ROWS = BB * SS;          // 8192
constexpr int LDY = 640;               // yv row: y(512) | pad(128, garbage ok)

// ---- workspace layout (bytes) ----
constexpr size_t XB_OFF  = 0;                          // bf16 xb  [8192][512]   (8 MB)
constexpr size_t WQB_OFF = XB_OFF  + 8388608;          // bf16 wqb [512][2048]   (2 MB)
constexpr size_t WKB_OFF = WQB_OFF + 2097152;          // bf16 wkb [512][2048]   (2 MB)
constexpr size_t WT2_OFF = WKB_OFF + 2097152;          // bf16 wt2 [640][512]
constexpr size_t MTP_OFF = WT2_OFF + 655360;           // fp32 mt partials [8][512][512] (8 MB)
constexpr size_t YV_OFF  = MTP_OFF + 8388608;          // bf16 yv  [8192][640]   (10 MB)
constexpr size_t VT_OFF  = YV_OFF  + 10485760;         // bf16 vt  [4][64][2048] (1 MB)
constexpr size_t PRT_OFF = VT_OFF  + 1048576;          // bf16 O' partials [4][16][2048][64] (16 MB)
constexpr size_t STA_OFF = PRT_OFF + 16777216;         // fp32 stats [4][16][2048][2] (1 MB)

__device__ __forceinline__ void async_copy16(const bf16* g, const unsigned short* l) {
    __builtin_amdgcn_global_load_lds((const __attribute__((address_space(1))) void*)g,
                                     (__attribute__((address_space(3))) void*)l, 16, 0, 0);
}

// ---------------- fused prep: convert x | convert Wq,Wk | transpose Wv ----------------
__global__ __launch_bounds__(256) void prep(const float* __restrict__ x,
                                            const float* __restrict__ Wq,
                                            const float* __restrict__ Wk,
                                            const float* __restrict__ Wv,
                                            bf16* __restrict__ xb,
                                            bf16* __restrict__ wqb,
                                            bf16* __restrict__ wkb,
                                            bf16* __restrict__ wt2) {
    __shared__ float tile[32][33];
    const int bid = blockIdx.x;
    const int tid = threadIdx.x;

    if (bid < 4096) {
        int i = bid * 256 + tid;                     // over 1048576 float4 groups
        float4 v = reinterpret_cast<const float4*>(x)[i];
        union { bf16 h[4]; ushort4 u; } cv;
        cv.h[0] = __float2bfloat16(v.x);
        cv.h[1] = __float2bfloat16(v.y);
        cv.h[2] = __float2bfloat16(v.z);
        cv.h[3] = __float2bfloat16(v.w);
        reinterpret_cast<ushort4*>(xb)[i] = cv.u;
    } else if (bid < 6144) {
        int i = (bid - 4096) * 256 + tid;            // over 524288 float4 groups
        const float* src = (i < 262144) ? Wq : Wk;
        bf16* dst = (i < 262144) ? wqb : wkb;
        int j = (i < 262144) ? i : i - 262144;
        float4 v = reinterpret_cast<const float4*>(src)[j];
        union { bf16 h[4]; ushort4 u; } cv;
        cv.h[0] = __float2bfloat16(v.x);
        cv.h[1] = __float2bfloat16(v.y);
        cv.h[2] = __float2bfloat16(v.z);
        cv.h[3] = __float2bfloat16(v.w);
        reinterpret_cast<ushort4*>(dst)[j] = cv.u;
    } else {
        int idx = bid - 6144;                        // 0..31
        int n0 = (idx & 1) * 32;
        int k0 = (idx >> 1) * 32;
        int nn = tid & 31, kk8 = tid >> 5;
        #pragma unroll
        for (int p = 0; p < 4; ++p) {
            int k = p * 8 + kk8;
            tile[k][nn] = Wv[(long long)(k0 + k) * 64 + n0 + nn];
        }
        __syncthreads();
        int kk = tid & 31, nn8 = tid >> 5;
        #pragma unroll
        for (int p = 0; p < 4; ++p) {
            int n = p * 8 + nn8;
            wt2[(long long)(512 + n0 + n) * 512 + k0 + kk] = __float2bfloat16(tile[kk][n]);
        }
    }
}

// ---------------- Mt partial GEMM: Mt[j][i] = sum_n wkb[j][n]*wqb[i][n], split-K 8 ----------------
// 64x64 tiles, 4-wave blocks: 512 blocks (2/CU, ALL CUs busy; was 128 blocks = half chip idle).
// Plane-major XCD swizzle: each XCD owns one split-K plane. k-order unchanged -> bit-identical.
__global__ __launch_bounds__(256) void gemm_mt(const bf16* __restrict__ A,
                                               const bf16* __restrict__ Bt,
                                               float* __restrict__ Cp) {
    __shared__ __align__(16) unsigned short As[64 * 64];
    __shared__ __align__(16) unsigned short Bs[64 * 64];

    const int tid = threadIdx.x;
    const int lane = tid & 63, wave = tid >> 6;      // 4 waves

    // 512 = 8 XCD x 64; z = XCD
    const int wg = (blockIdx.x & 7) * 64 + (blockIdx.x >> 3);
    const int z = wg >> 6;               // split-K plane 0..7
    const int tile = wg & 63;
    const long long m0 = (long long)(tile >> 3) * 64;
    const long long n0 = (long long)(tile & 7) * 64;
    const int koff = z * 256;

    const int rIn = lane >> 3;
    const int cSwz = ((lane & 7) ^ rIn) * 8;
    const int wm0 = (wave >> 1) * 32, wn0 = (wave & 1) * 32;
    const int l15 = lane & 15, quad = lane >> 4;
    const int sw7 = l15 & 7;

    floatx4 acc[2][2] = {};

    for (int k0 = koff; k0 < koff + 256; k0 += 64) {
        #pragma unroll
        for (int t0 = 0; t0 < 4; ++t0) {             // 16 slots: 8 A + 8 B (64 rows each)
            int t = t0 * 4 + wave;
            if (t < 8)
                async_copy16(A + (m0 + t * 8 + rIn) * 2048LL + k0 + cSwz, &As[t * 512]);
            else
                async_copy16(Bt + (n0 + (t - 8) * 8 + rIn) * 2048LL + k0 + cSwz, &Bs[(t - 8) * 512]);
        }
        __syncthreads();
        #pragma unroll
        for (int sk = 0; sk < 2; ++sk) {
            const int rchunk = (((sk << 2) | quad) ^ sw7) * 8;
            bf16x8 af[2], bfr[2];
            #pragma unroll
            for (int mi = 0; mi < 2; ++mi)
                af[mi] = *reinterpret_cast<const bf16x8*>(&As[(wm0 + mi * 16 + l15) * 64 + rchunk]);
            #pragma unroll
            for (int ni = 0; ni < 2; ++ni)
                bfr[ni] = *reinterpret_cast<const bf16x8*>(&Bs[(wn0 + ni * 16 + l15) * 64 + rchunk]);
            #pragma unroll
            for (int mi = 0; mi < 2; ++mi)
                #pragma unroll
                for (int ni = 0; ni < 2; ++ni)
                    acc[mi][ni] = __builtin_amdgcn_mfma_f32_16x16x32_bf16(af[mi], bfr[ni],
                                                                          acc[mi][ni], 0, 0, 0);
        }
        __syncthreads();
    }

    float* C = Cp + (long long)z * 262144;
    #pragma unroll
    for (int mi = 0; mi < 2; ++mi) {
        long long row0 = m0 + wm0 + mi * 16 + quad * 4;
        #pragma unroll
        for (int ni = 0; ni < 2; ++ni) {
            long long col = n0 + wn0 + ni * 16 + l15;
            #pragma unroll
            for (int r = 0; r < 4; ++r)
                C[(row0 + r) * 512 + col] = acc[mi][ni][r];
        }
    }
}

// ---------------- reduce Mt partials -> wt2 rows 0..511 (bf16) ----------------
__global__ __launch_bounds__(256) void reduce_mt(const float4* __restrict__ part,
                                                 bf16* __restrict__ wt2) {
    int i = blockIdx.x * 256 + threadIdx.x;          // over 65536 float4 groups
    float4 s = {0.f, 0.f, 0.f, 0.f};
    #pragma unroll
    for (int t = 0; t < 8; ++t) {
        float4 a = part[(long long)t * 65536 + i];
        s.x += a.x; s.y += a.y; s.z += a.z; s.w += a.w;
    }
    union { bf16 h[4]; ushort4 u; } cv;
    cv.h[0] = __float2bfloat16(s.x);
    cv.h[1] = __float2bfloat16(s.y);
    cv.h[2] = __float2bfloat16(s.z);
    cv.h[3] = __float2bfloat16(s.w);
    reinterpret_cast<ushort4*>(wt2)[i] = cv.u;
}

// ---------------- yv GEMM: yv[8192][0..512) = xb . wt2^T, K=512 ----------------
// 64x128 tiles, 4-wave blocks: 640 blocks (2.5/CU; was 320 = 1.25/CU with a 25% tail round).
// m-major XCD swizzle (A panels L2-local). n-tile 4 writes v TRANSPOSED to vt (even waves).
// k ascending, BK=64, sk 0..1 -> accumulation order bit-identical to the 128x128 version.
__global__ __launch_bounds__(256) void gemm_proj(const bf16* __restrict__ A,
                                                 const bf16* __restrict__ Bt,
                                                 bf16* __restrict__ C,
                                                 bf16* __restrict__ vt) {
    __shared__ __align__(16) unsigned short As[8 * 512];    // 64 rows (8 KB)
    __shared__ __align__(16) unsigned short Bs[16 * 512];   // 128 rows (16 KB)

    const int tid = threadIdx.x;
    const int lane = tid & 63, wave = tid >> 6;      // 4 waves

    // bijective XCD swizzle: 640 blocks, q = 80; m-major enumeration
    const int wg = (blockIdx.x & 7) * 80 + (blockIdx.x >> 3);
    const long long m0 = (long long)(wg / 5) * 64;
    const int ntile = wg % 5;
    const long long n0 = (long long)ntile * 128;

    const int rIn = lane >> 3;
    const int cSwz = ((lane & 7) ^ rIn) * 8;
    const int wm0 = (wave >> 1) * 32, wn0 = (wave & 1) * 64;
    const int l15 = lane & 15, quad = lane >> 4;
    const int sw7 = l15 & 7;

    floatx4 acc[2][4] = {};

    for (int k0 = 0; k0 < DIN; k0 += 64) {
        #pragma unroll
        for (int t0 = 0; t0 < 6; ++t0) {             // 24 slots: 8 A (64 rows) + 16 B (128 rows)
            int t = t0 * 4 + wave;
            if (t < 8)
                async_copy16(A + (m0 + t * 8 + rIn) * (long long)DIN + k0 + cSwz, &As[t * 512]);
            else
                async_copy16(Bt + (n0 + (t - 8) * 8 + rIn) * (long long)DIN + k0 + cSwz,
                             &Bs[(t - 8) * 512]);
        }
        __syncthreads();
        #pragma unroll
        for (int sk = 0; sk < 2; ++sk) {
            const int rchunk = (((sk << 2) | quad) ^ sw7) * 8;
            bf16x8 af[2], bfr[4];
            #pragma unroll
            for (int mi = 0; mi < 2; ++mi)
                af[mi] = *reinterpret_cast<const bf16x8*>(&As[(wm0 + mi * 16 + l15) * 64 + rchunk]);
            #pragma unroll
            for (int ni = 0; ni < 4; ++ni)
                bfr[ni] = *reinterpret_cast<const bf16x8*>(&Bs[(wn0 + ni * 16 + l15) * 64 + rchunk]);
            #pragma unroll
            for (int mi = 0; mi < 2; ++mi)
                #pragma unroll
                for (int ni = 0; ni < 4; ++ni)
                    acc[mi][ni] = __builtin_amdgcn_mfma_f32_16x16x32_bf16(af[mi], bfr[ni],
                                                                          acc[mi][ni], 0, 0, 0);
        }
        __syncthreads();
    }

    if (ntile < 4) {
        // y columns -> yv (row stride LDY)
        #pragma unroll
        for (int mi = 0; mi < 2; ++mi) {
            long long row0 = m0 + wm0 + mi * 16 + quad * 4;
            #pragma unroll
            for (int ni = 0; ni < 4; ++ni) {
                long long col = n0 + wn0 + ni * 16 + l15;
                #pragma unroll
                for (int r = 0; r < 4; ++r)
                    C[(row0 + r) * (long long)LDY + col] = __float2bfloat16(acc[mi][ni][r]);
            }
        }
    } else if (!(wave & 1)) {
        // v columns (even waves, j = ni*16+l15 in [0,64)) -> vt[b][j][s] transposed
        const int b = (int)(m0 >> 11);
        const int sbase = ((int)m0 & 2047) + wm0;
        #pragma unroll
        for (int mi = 0; mi < 2; ++mi) {
            int s0 = sbase + mi * 16 + quad * 4;
            #pragma unroll
            for (int ni = 0; ni < 4; ++ni) {
                int j = ni * 16 + l15;
                union { bf16 h[4]; ushort4 u; } cv;
                #pragma unroll
                for (int r = 0; r < 4; ++r)
                    cv.h[r] = __float2bfloat16(acc[mi][ni][r]);
                *reinterpret_cast<ushort4*>(vt + ((long long)(b * DVV + j)) * SS + s0) = cv.u;
            }
        }
    }
}

// ---------------- fused causal attention tile, M=64 x N=128, 4-wave blocks ----------------
// (unchanged from round 6 — best-known attn config)
__global__ __launch_bounds__(256) void attn_fused(const bf16* __restrict__ yv,
                                                  const bf16* __restrict__ xb,
                                                  const bf16* __restrict__ vt,
                                                  bf16* __restrict__ part,
                                                  float* __restrict__ stats) {
    constexpr int BK = 64;
    constexpr float SCALE = 0.022097086912079608f;   // 1/sqrt(2048)

    __shared__ __align__(16) char smem[24576];
    unsigned short* As = (unsigned short*)smem;             // [8*512]  QK A staging (8 KB, 64 rows)
    unsigned short* Bs = (unsigned short*)(smem + 8192);    // [16*512] QK B staging (16 KB, 128 rows)
    unsigned short* Ps = (unsigned short*)smem;             // [64][72] P~ half (overlay, post-QK)
    unsigned short* Vs = (unsigned short*)(smem + 9216);    // [64][72] V half (overlay)
    float* smax = (float*)(smem + 18432);                   // [64][2]
    float* ssum = (float*)(smem + 18944);                   // [64][2]

    // XCD swizzle (272 = 8*34, bijective) + causal half-tile decode
    const int wg = (blockIdx.x & 7) * 34 + (blockIdx.x >> 3);
    int by = 0, c = 0;
    while (c + (by >> 1) + 1 <= wg) { c += (by >> 1) + 1; ++by; }
    const int bx = wg - c;
    const int b = blockIdx.z;

    const bf16* A  = yv + (long long)b * SS * LDY;           // y rows (q role)
    const bf16* Bt = xb + (long long)b * SS * 512;           // x rows (k role)

    const int tid = threadIdx.x;
    const int lane = tid & 63, wave = tid >> 6;               // 4 waves
    const long long m0 = (long long)by * 64;
    const long long n0 = (long long)bx * 128;

    const int rIn = lane >> 3;
    const int cSwz = ((lane & 7) ^ rIn) * 8;
    const int wm0 = (wave >> 1) * 32, wn0 = (wave & 1) * 64;  // 2x2 waves over 64x128
    const int l15 = lane & 15, quad = lane >> 4;
    const int sw7 = l15 & 7;

    floatx4 acc[2][4] = {};

    // prefetch full V chunk V[64][n0..n0+128) to registers: 4 x uint4 per thread
    uint4 vreg[4];
    {
        int j = tid >> 2;
        int ch = tid & 3;
        #pragma unroll
        for (int p = 0; p < 4; ++p)
            vreg[p] = *reinterpret_cast<const uint4*>(
                vt + ((long long)b * DVV + j) * SS + n0 + (ch + p * 4) * 8);
    }

    auto issue = [&](int k0) {
        #pragma unroll
        for (int t0 = 0; t0 < 6; ++t0) {             // 24 slots: 8 A (64 rows) + 16 B (128 rows)
            int t = t0 * 4 + wave;
            if (t < 8)
                async_copy16(A + (m0 + t * 8 + rIn) * (long long)LDY + k0 + cSwz,
                             &As[t * 512]);
            else
                async_copy16(Bt + (n0 + (t - 8) * 8 + rIn) * 512LL + k0 + cSwz,
                             &Bs[(t - 8) * 512]);
        }
    };

    for (int it = 0; it < DIN / BK; ++it) {      // 8 iterations (K=512)
        issue(it * BK);
        __syncthreads();                          // loads landed
        __builtin_amdgcn_s_setprio(1);
        #pragma unroll
        for (int sk = 0; sk < 2; ++sk) {
            const int rchunk = (((sk << 2) | quad) ^ sw7) * 8;
            bf16x8 af[2], bfr[4];
            #pragma unroll
            for (int mi = 0; mi < 2; ++mi)
                af[mi] = *reinterpret_cast<const bf16x8*>(
                    &As[(wm0 + mi * 16 + l15) * BK + rchunk]);
            #pragma unroll
            for (int ni = 0; ni < 4; ++ni)
                bfr[ni] = *reinterpret_cast<const bf16x8*>(
                    &Bs[(wn0 + ni * 16 + l15) * BK + rchunk]);
            #pragma unroll
            for (int mi = 0; mi < 2; ++mi)
                #pragma unroll
                for (int ni = 0; ni < 4; ++ni)
                    acc[mi][ni] = __builtin_amdgcn_mfma_f32_16x16x32_bf16(af[mi], bfr[ni],
                                                                          acc[mi][ni], 0, 0, 0);
        }
        __builtin_amdgcn_s_setprio(0);
        __syncthreads();                          // all reads done before next issue
    }
    // QK done. S in acc: local row = wm0 + mi*16 + quad*4 + r, local col = wn0 + ni*16 + l15.

    // scale + causal mask (tiles straddling the diagonal: n0+127 > m0)
    const bool diag = (n0 + 127 > m0);
    #pragma unroll
    for (int mi = 0; mi < 2; ++mi)
        #pragma unroll
        for (int ni = 0; ni < 4; ++ni)
            #pragma unroll
            for (int r = 0; r < 4; ++r) {
                float v = acc[mi][ni][r] * SCALE;
                if (diag) {
                    int grow = (int)m0 + wm0 + mi * 16 + quad * 4 + r;
                    int gcol = (int)n0 + wn0 + ni * 16 + l15;
                    if (gcol > grow) v = -INFINITY;
                }
                acc[mi][ni][r] = v;
            }

    // row max within tile (2 col-waves per row)
    float rmax[2][4];
    #pragma unroll
    for (int mi = 0; mi < 2; ++mi)
        #pragma unroll
        for (int r = 0; r < 4; ++r) {
            float m = fmaxf(fmaxf(acc[mi][0][r], acc[mi][1][r]),
                            fmaxf(acc[mi][2][r], acc[mi][3][r]));
            #pragma unroll
            for (int msk = 8; msk >= 1; msk >>= 1) m = fmaxf(m, __shfl_xor(m, msk));
            rmax[mi][r] = m;
            if (l15 == 0) smax[(wm0 + mi * 16 + quad * 4 + r) * 2 + (wave & 1)] = m;
        }
    __syncthreads();
    #pragma unroll
    for (int mi = 0; mi < 2; ++mi)
        #pragma unroll
        for (int r = 0; r < 4; ++r) {
            int row = wm0 + mi * 16 + quad * 4 + r;
            rmax[mi][r] = fmaxf(smax[row * 2], smax[row * 2 + 1]);
        }

    // exp + row sums
    #pragma unroll
    for (int mi = 0; mi < 2; ++mi)
        #pragma unroll
        for (int r = 0; r < 4; ++r) {
            float s = 0.f;
            #pragma unroll
            for (int ni = 0; ni < 4; ++ni) {
                float p = __expf(acc[mi][ni][r] - rmax[mi][r]);
                acc[mi][ni][r] = p;
                s += p;
            }
            #pragma unroll
            for (int msk = 8; msk >= 1; msk >>= 1) s += __shfl_xor(s, msk);
            if (l15 == 0) ssum[(wm0 + mi * 16 + quad * 4 + r) * 2 + (wave & 1)] = s;
        }

    // half 0: even waves (wn0==0) write P~ cols 0..63 into Ps[64][72]
    if ((wave & 1) == 0) {
        #pragma unroll
        for (int mi = 0; mi < 2; ++mi) {
            int row = wm0 + mi * 16 + quad * 4;
            #pragma unroll
            for (int ni = 0; ni < 4; ++ni) {
                int col = ni * 16 + l15;
                #pragma unroll
                for (int r = 0; r < 4; ++r)
                    Ps[(row + r) * 72 + col] =
                        (unsigned short)__bfloat16_as_ushort(__float2bfloat16(acc[mi][ni][r]));
            }
        }
    }
    // write V half 0 (global chunks 0..7) xor-swizzled into Vs[64][72]
    {
        int j = tid >> 2;
        int ch = tid & 3;
        #pragma unroll
        for (int pp = 0; pp < 2; ++pp) {
            int chh = ch + pp * 4;                               // within-half chunk 0..7
            *reinterpret_cast<uint4*>(&Vs[j * 72 + ((chh ^ (j & 7)) * 8)]) = vreg[pp];
        }
    }
    __syncthreads();

    // per-row stats out (m, l) for 64 rows
    if (tid < 64) {
        float m = fmaxf(smax[tid * 2], smax[tid * 2 + 1]);
        float l = ssum[tid * 2] + ssum[tid * 2 + 1];
        long long o = (((long long)b * 16 + bx) * SS + m0 + tid) * 2;
        stats[o] = m;
        stats[o + 1] = l;
    }

    // O' = P~ . V  (M=64, N=64, K=128) in two halves; global k-chunk order 0,1,2,3
    const int wmv = wave * 16;
    floatx4 accO[4] = {};
    __builtin_amdgcn_s_setprio(1);
    #pragma unroll
    for (int sk = 0; sk < 2; ++sk) {                       // half 0: kc = sk
        bf16x8 af = *reinterpret_cast<const bf16x8*>(
            &Ps[(wmv + l15) * 72 + sk * 32 + quad * 8]);
        #pragma unroll
        for (int ni = 0; ni < 4; ++ni) {
            bf16x8 bfv = *reinterpret_cast<const bf16x8*>(
                &Vs[(ni * 16 + l15) * 72 + ((((sk << 2) | quad)) ^ sw7) * 8]);
            accO[ni] = __builtin_amdgcn_mfma_f32_16x16x32_bf16(af, bfv, accO[ni], 0, 0, 0);
        }
    }
    __builtin_amdgcn_s_setprio(0);
    __syncthreads();

    // half 1: odd waves (wn0==64) write P~ cols 64..127; V half 1 (chunks 8..15)
    if ((wave & 1) == 1) {
        #pragma unroll
        for (int mi = 0; mi < 2; ++mi) {
            int row = wm0 + mi * 16 + quad * 4;
            #pragma unroll
            for (int ni = 0; ni < 4; ++ni) {
                int col = ni * 16 + l15;
                #pragma unroll
                for (int r = 0; r < 4; ++r)
                    Ps[(row + r) * 72 + col] =
                        (unsigned short)__bfloat16_as_ushort(__float2bfloat16(acc[mi][ni][r]));
            }
        }
    }
    {
        int j = tid >> 2;
        int ch = tid & 3;
        #pragma unroll
        for (int pp = 0; pp < 2; ++pp) {
            int chh = ch + pp * 4;                               // within-half chunk 0..7
            *reinterpret_cast<uint4*>(&Vs[j * 72 + ((chh ^ (j & 7)) * 8)]) = vreg[2 + pp];
        }
    }
    __syncthreads();

    __builtin_amdgcn_s_setprio(1);
    #pragma unroll
    for (int sk = 0; sk < 2; ++sk) {                       // half 1: kc = 2 + sk
        bf16x8 af = *reinterpret_cast<const bf16x8*>(
            &Ps[(wmv + l15) * 72 + sk * 32 + quad * 8]);
        #pragma unroll
        for (int ni = 0; ni < 4; ++ni) {
            bf16x8 bfv = *reinterpret_cast<const bf16x8*>(
                &Vs[(ni * 16 + l15) * 72 + ((((sk << 2) | quad)) ^ sw7) * 8]);
            accO[ni] = __builtin_amdgcn_mfma_f32_16x16x32_bf16(af, bfv, accO[ni], 0, 0, 0);
        }
    }
    __builtin_amdgcn_s_setprio(0);

    #pragma unroll
    for (int ni = 0; ni < 4; ++ni)
        #pragma unroll
        for (int r = 0; r < 4; ++r)
            part[(((long long)b * 16 + bx) * SS + m0 + wmv + quad * 4 + r) * 64 + ni * 16 + l15]
                = __float2bfloat16(accO[ni][r]);
}

// ---------------- combine k-tile partials (vectorized x8 bf16 loads) ----------------
__global__ __launch_bounds__(256) void combine(const bf16* __restrict__ part,
                                               const float* __restrict__ stats,
                                               float* __restrict__ out) {
    int tid = blockIdx.x * 256 + threadIdx.x;   // over 8192*8
    int row = tid >> 3;
    int col8 = (tid & 7) * 8;
    int b = row >> 11, s = row & (SS - 1);
    int nt = (s >> 7) + 1;                      // live k-tiles for this row

    float m[16], l[16], M = -INFINITY;
    #pragma unroll
    for (int t = 0; t < 16; ++t)
        if (t < nt) {
            long long o = (((long long)b * 16 + t) * SS + s) * 2;
            m[t] = stats[o];
            l[t] = stats[o + 1];
            M = fmaxf(M, m[t]);
        }
    float O[8] = {};
    float L = 0.f;
    #pragma unroll
    for (int t = 0; t < 16; ++t)
        if (t < nt) {
            float wgt = __expf(m[t] - M);
            L += wgt * l[t];
            union { uint4 q; unsigned short u[8]; } ld;
            ld.q = *reinterpret_cast<const uint4*>(
                part + (((long long)b * 16 + t) * SS + s) * 64 + col8);
            #pragma unroll
            for (int j = 0; j < 8; ++j)
                O[j] += wgt * __uint_as_float((unsigned)ld.u[j] << 16);
        }
    float rinv = 1.0f / L;
    float4 o0 = {O[0] * rinv, O[1] * rinv, O[2] * rinv, O[3] * rinv};
    float4 o1 = {O[4] * rinv, O[5] * rinv, O[6] * rinv, O[7] * rinv};
    float4* dst = reinterpret_cast<float4*>(out + (long long)row * 64 + col8);
    dst[0] = o0;
    dst[1] = o1;
}

extern "C" void kernel_launch(void* const* d_in, const int* in_sizes, int n_in,
                              void* d_out, int out_size, void* d_ws, size_t ws_size,
                              hipStream_t stream) {
    const float* x  = (const float*)d_in[0];
    const float* Wq = (const float*)d_in[1];
    const float* Wk = (const float*)d_in[2];
    const float* Wv = (const float*)d_in[3];
    float* out = (float*)d_out;

    char* w = (char*)d_ws;
    bf16* xb   = (bf16*)(w + XB_OFF);
    bf16* wqb  = (bf16*)(w + WQB_OFF);
    bf16* wkb  = (bf16*)(w + WKB_OFF);
    bf16* wt2  = (bf16*)(w + WT2_OFF);
    float* mtp = (float*)(w + MTP_OFF);
    bf16* yv   = (bf16*)(w + YV_OFF);
    bf16* vt   = (bf16*)(w + VT_OFF);
    bf16* part = (bf16*)(w + PRT_OFF);
    float* stats = (float*)(w + STA_OFF);

    // 1. fused prep: x->xb, Wq/Wk->bf16, Wv->wt2 rows 512..575 (transposed)
    prep<<<6176, 256, 0, stream>>>(x, Wq, Wk, Wv, xb, wqb, wkb, wt2);

    // 2. Mt = Wk·Wq^T [512x512] (split-K 8 partials + reduce) -> wt2 rows 0..511
    gemm_mt<<<512, 256, 0, stream>>>(wkb, wqb, mtp);
    reduce_mt<<<65536 / 256, 256, 0, stream>>>((const float4*)mtp, wt2);

    // 3. yv = xb·wt2^T (y cols) + vt written transposed directly from the v N-tile
    gemm_proj<<<640, 256, 0, stream>>>(xb, wt2, yv, vt);

    // 4. fused attention: M=64 x N=128 4-wave tiles, grid 1088
    attn_fused<<<dim3(272, 1, BB), 256, 0, stream>>>(yv, xb, vt, part, stats);

    // 5. combine partials -> out
    combine<<<ROWS * 8 / 256, 256, 0, stream>>>(part, stats, out);
}

// Round 8
// 136.424 us; speedup vs baseline: 1.2538x; 1.0013x over previous
//
#include <hip/hip_runtime.h>
#include <hip/hip_bf16.h>
#include <math.h>

using bf16 = __hip_bfloat16;
typedef __bf16 bf16x8 __attribute__((ext_vector_type(8)));
typedef float floatx4 __attribute__((ext_vector_type(4)));

// Problem dims
constexpr int BB = 4, SS = 2048, DIN = 512, DKK = 2048, DVV = 64;
constexpr int ROWS = BB * SS;          // 8192
constexpr int LDY = 640;               // yv row: y(512) | pad(128, garbage ok)

// ---- workspace layout (bytes) ----
constexpr size_t XB_OFF  = 0;                          // bf16 xb  [8192][512]   (8 MB)
constexpr size_t WQB_OFF = XB_OFF  + 8388608;          // (unused now)
constexpr size_t WKB_OFF = WQB_OFF + 2097152;          // (unused now)
constexpr size_t WT2_OFF = WKB_OFF + 2097152;          // bf16 wt2 [640][512]
constexpr size_t MTP_OFF = WT2_OFF + 655360;           // fp32 mt partials [8][512][512] (8 MB)
constexpr size_t YV_OFF  = MTP_OFF + 8388608;          // bf16 yv  [8192][640]   (10 MB)
constexpr size_t VT_OFF  = YV_OFF  + 10485760;         // bf16 vt  [4][64][2048] (1 MB)
constexpr size_t PRT_OFF = VT_OFF  + 1048576;          // bf16 O' partials [4][16][2048][64] (16 MB)
constexpr size_t STA_OFF = PRT_OFF + 16777216;         // fp32 stats [4][16][2048][2] (1 MB)

__device__ __forceinline__ void async_copy16(const bf16* g, const unsigned short* l) {
    __builtin_amdgcn_global_load_lds((const __attribute__((address_space(1))) void*)g,
                                     (__attribute__((address_space(3))) void*)l, 16, 0, 0);
}

// ---------------- fused prep + Mt GEMM -------------------------------------------------
// blocks [0,512):     Mt split-K GEMM (64x64 tiles, 4-wave), staging DIRECTLY from fp32
//                     Wq/Wk with inline bf16 convert (identical RNE rounding -> Mt bit-identical;
//                     wqb/wkb round-trip eliminated). Dispatched FIRST so the memory-bound
//                     x-convert blocks overlap this latency-bound phase.
// blocks [512,4608):  x -> xb bf16 convert
// blocks [4608,4640): Wv transpose -> wt2 rows 512..575
__global__ __launch_bounds__(256) void prep_mt(const float* __restrict__ x,
                                               const float* __restrict__ Wq,
                                               const float* __restrict__ Wk,
                                               const float* __restrict__ Wv,
                                               bf16* __restrict__ xb,
                                               bf16* __restrict__ wt2,
                                               float* __restrict__ Cp) {
    __shared__ __align__(16) char sm[16384];
    const int bid = blockIdx.x;
    const int tid = threadIdx.x;

    if (bid < 512) {
        unsigned short* As = (unsigned short*)sm;            // 64x64 bf16 (8 KB)
        unsigned short* Bs = (unsigned short*)(sm + 8192);   // 64x64 bf16 (8 KB)
        const int lane = tid & 63, wave = tid >> 6;

        // 512 = 8 XCD x 64; z = split-K plane
        const int wg = (bid & 7) * 64 + (bid >> 3);
        const int z = wg >> 6;
        const int tile = wg & 63;
        const long long m0 = (long long)(tile >> 3) * 64;
        const long long n0 = (long long)(tile & 7) * 64;
        const int koff = z * 256;

        const int rIn = lane >> 3;
        const int cSwzE = ((lane & 7) ^ rIn) * 8;            // pre-swizzled source col (elements)
        const int wm0 = (wave >> 1) * 32, wn0 = (wave & 1) * 32;
        const int l15 = lane & 15, quad = lane >> 4;
        const int sw7 = l15 & 7;

        floatx4 acc[2][2] = {};

        for (int k0 = koff; k0 < koff + 256; k0 += 64) {
            #pragma unroll
            for (int t0 = 0; t0 < 4; ++t0) {                 // 16 slots: 8 A(Wk) + 8 B(Wq)
                int t = t0 * 4 + wave;
                const float* src = (t < 8)
                    ? Wk + (m0 + t * 8 + rIn) * 2048LL + k0 + cSwzE
                    : Wq + (n0 + (t - 8) * 8 + rIn) * 2048LL + k0 + cSwzE;
                float4 f0 = *reinterpret_cast<const float4*>(src);
                float4 f1 = *reinterpret_cast<const float4*>(src + 4);
                union { bf16 h[8]; uint4 u; } cv;
                cv.h[0] = __float2bfloat16(f0.x);
                cv.h[1] = __float2bfloat16(f0.y);
                cv.h[2] = __float2bfloat16(f0.z);
                cv.h[3] = __float2bfloat16(f0.w);
                cv.h[4] = __float2bfloat16(f1.x);
                cv.h[5] = __float2bfloat16(f1.y);
                cv.h[6] = __float2bfloat16(f1.z);
                cv.h[7] = __float2bfloat16(f1.w);
                unsigned short* dst = (t < 8) ? &As[t * 512 + lane * 8]
                                              : &Bs[(t - 8) * 512 + lane * 8];
                *reinterpret_cast<uint4*>(dst) = cv.u;
            }
            __syncthreads();
            #pragma unroll
            for (int sk = 0; sk < 2; ++sk) {
                const int rchunk = (((sk << 2) | quad) ^ sw7) * 8;
                bf16x8 af[2], bfr[2];
                #pragma unroll
                for (int mi = 0; mi < 2; ++mi)
                    af[mi] = *reinterpret_cast<const bf16x8*>(&As[(wm0 + mi * 16 + l15) * 64 + rchunk]);
                #pragma unroll
                for (int ni = 0; ni < 2; ++ni)
                    bfr[ni] = *reinterpret_cast<const bf16x8*>(&Bs[(wn0 + ni * 16 + l15) * 64 + rchunk]);
                #pragma unroll
                for (int mi = 0; mi < 2; ++mi)
                    #pragma unroll
                    for (int ni = 0; ni < 2; ++ni)
                        acc[mi][ni] = __builtin_amdgcn_mfma_f32_16x16x32_bf16(af[mi], bfr[ni],
                                                                              acc[mi][ni], 0, 0, 0);
            }
            __syncthreads();
        }

        float* C = Cp + (long long)z * 262144;
        #pragma unroll
        for (int mi = 0; mi < 2; ++mi) {
            long long row0 = m0 + wm0 + mi * 16 + quad * 4;
            #pragma unroll
            for (int ni = 0; ni < 2; ++ni) {
                long long col = n0 + wn0 + ni * 16 + l15;
                #pragma unroll
                for (int r = 0; r < 4; ++r)
                    C[(row0 + r) * 512 + col] = acc[mi][ni][r];
            }
        }
    } else if (bid < 4608) {
        int i = (bid - 512) * 256 + tid;                     // over 1048576 float4 groups
        float4 v = reinterpret_cast<const float4*>(x)[i];
        union { bf16 h[4]; ushort4 u; } cv;
        cv.h[0] = __float2bfloat16(v.x);
        cv.h[1] = __float2bfloat16(v.y);
        cv.h[2] = __float2bfloat16(v.z);
        cv.h[3] = __float2bfloat16(v.w);
        reinterpret_cast<ushort4*>(xb)[i] = cv.u;
    } else {
        float (*tile)[33] = (float (*)[33])sm;               // 32x33 fp32 (4224 B)
        int idx = bid - 4608;                                // 0..31
        int n0 = (idx & 1) * 32;
        int k0 = (idx >> 1) * 32;
        int nn = tid & 31, kk8 = tid >> 5;
        #pragma unroll
        for (int p = 0; p < 4; ++p) {
            int k = p * 8 + kk8;
            tile[k][nn] = Wv[(long long)(k0 + k) * 64 + n0 + nn];
        }
        __syncthreads();
        int kk = tid & 31, nn8 = tid >> 5;
        #pragma unroll
        for (int p = 0; p < 4; ++p) {
            int n = p * 8 + nn8;
            wt2[(long long)(512 + n0 + n) * 512 + k0 + kk] = __float2bfloat16(tile[kk][n]);
        }
    }
}

// ---------------- reduce Mt partials -> wt2 rows 0..511 (bf16) ----------------
__global__ __launch_bounds__(256) void reduce_mt(const float4* __restrict__ part,
                                                 bf16* __restrict__ wt2) {
    int i = blockIdx.x * 256 + threadIdx.x;          // over 65536 float4 groups
    float4 s = {0.f, 0.f, 0.f, 0.f};
    #pragma unroll
    for (int t = 0; t < 8; ++t) {
        float4 a = part[(long long)t * 65536 + i];
        s.x += a.x; s.y += a.y; s.z += a.z; s.w += a.w;
    }
    union { bf16 h[4]; ushort4 u; } cv;
    cv.h[0] = __float2bfloat16(s.x);
    cv.h[1] = __float2bfloat16(s.y);
    cv.h[2] = __float2bfloat16(s.z);
    cv.h[3] = __float2bfloat16(s.w);
    reinterpret_cast<ushort4*>(wt2)[i] = cv.u;
}

// ---------------- yv GEMM: yv[8192][0..512) = xb . wt2^T, K=512 ----------------
// (unchanged from round 7: 64x128 tiles, 640 blocks, vt fused transpose on n-tile 4)
__global__ __launch_bounds__(256) void gemm_proj(const bf16* __restrict__ A,
                                                 const bf16* __restrict__ Bt,
                                                 bf16* __restrict__ C,
                                                 bf16* __restrict__ vt) {
    __shared__ __align__(16) unsigned short As[8 * 512];    // 64 rows (8 KB)
    __shared__ __align__(16) unsigned short Bs[16 * 512];   // 128 rows (16 KB)

    const int tid = threadIdx.x;
    const int lane = tid & 63, wave = tid >> 6;      // 4 waves

    // bijective XCD swizzle: 640 blocks, q = 80; m-major enumeration
    const int wg = (blockIdx.x & 7) * 80 + (blockIdx.x >> 3);
    const long long m0 = (long long)(wg / 5) * 64;
    const int ntile = wg % 5;
    const long long n0 = (long long)ntile * 128;

    const int rIn = lane >> 3;
    const int cSwz = ((lane & 7) ^ rIn) * 8;
    const int wm0 = (wave >> 1) * 32, wn0 = (wave & 1) * 64;
    const int l15 = lane & 15, quad = lane >> 4;
    const int sw7 = l15 & 7;

    floatx4 acc[2][4] = {};

    for (int k0 = 0; k0 < DIN; k0 += 64) {
        #pragma unroll
        for (int t0 = 0; t0 < 6; ++t0) {             // 24 slots: 8 A (64 rows) + 16 B (128 rows)
            int t = t0 * 4 + wave;
            if (t < 8)
                async_copy16(A + (m0 + t * 8 + rIn) * (long long)DIN + k0 + cSwz, &As[t * 512]);
            else
                async_copy16(Bt + (n0 + (t - 8) * 8 + rIn) * (long long)DIN + k0 + cSwz,
                             &Bs[(t - 8) * 512]);
        }
        __syncthreads();
        #pragma unroll
        for (int sk = 0; sk < 2; ++sk) {
            const int rchunk = (((sk << 2) | quad) ^ sw7) * 8;
            bf16x8 af[2], bfr[4];
            #pragma unroll
            for (int mi = 0; mi < 2; ++mi)
                af[mi] = *reinterpret_cast<const bf16x8*>(&As[(wm0 + mi * 16 + l15) * 64 + rchunk]);
            #pragma unroll
            for (int ni = 0; ni < 4; ++ni)
                bfr[ni] = *reinterpret_cast<const bf16x8*>(&Bs[(wn0 + ni * 16 + l15) * 64 + rchunk]);
            #pragma unroll
            for (int mi = 0; mi < 2; ++mi)
                #pragma unroll
                for (int ni = 0; ni < 4; ++ni)
                    acc[mi][ni] = __builtin_amdgcn_mfma_f32_16x16x32_bf16(af[mi], bfr[ni],
                                                                          acc[mi][ni], 0, 0, 0);
        }
        __syncthreads();
    }

    if (ntile < 4) {
        #pragma unroll
        for (int mi = 0; mi < 2; ++mi) {
            long long row0 = m0 + wm0 + mi * 16 + quad * 4;
            #pragma unroll
            for (int ni = 0; ni < 4; ++ni) {
                long long col = n0 + wn0 + ni * 16 + l15;
                #pragma unroll
                for (int r = 0; r < 4; ++r)
                    C[(row0 + r) * (long long)LDY + col] = __float2bfloat16(acc[mi][ni][r]);
            }
        }
    } else if (!(wave & 1)) {
        const int b = (int)(m0 >> 11);
        const int sbase = ((int)m0 & 2047) + wm0;
        #pragma unroll
        for (int mi = 0; mi < 2; ++mi) {
            int s0 = sbase + mi * 16 + quad * 4;
            #pragma unroll
            for (int ni = 0; ni < 4; ++ni) {
                int j = ni * 16 + l15;
                union { bf16 h[4]; ushort4 u; } cv;
                #pragma unroll
                for (int r = 0; r < 4; ++r)
                    cv.h[r] = __float2bfloat16(acc[mi][ni][r]);
                *reinterpret_cast<ushort4*>(vt + ((long long)(b * DVV + j)) * SS + s0) = cv.u;
            }
        }
    }
}

// ---------------- fused causal attention tile, M=64 x N=128, 4-wave, BK=128 ----------------
// Drain-iters halved vs round-6 (4 instead of 8; 32 MFMA/wave/iter). LDS 48 KB -> 2 blocks/CU
// with the 1088-block grid. k ascending (it*128 + sk*32) -> accumulation bit-identical.
// Softmax/PV/stats unchanged from round 6.
__global__ __launch_bounds__(256) void attn_fused(const bf16* __restrict__ yv,
                                                  const bf16* __restrict__ xb,
                                                  const bf16* __restrict__ vt,
                                                  bf16* __restrict__ part,
                                                  float* __restrict__ stats) {
    constexpr int BK = 128;
    constexpr float SCALE = 0.022097086912079608f;   // 1/sqrt(2048)

    __shared__ __align__(16) char smem[49152];
    unsigned short* As = (unsigned short*)smem;             // [64][128] QK A (16 KB)
    unsigned short* Bs = (unsigned short*)(smem + 16384);   // [128][128] QK B (32 KB)
    unsigned short* Ps = (unsigned short*)smem;             // [64][72] P~ half (overlay, post-QK)
    unsigned short* Vs = (unsigned short*)(smem + 9216);    // [64][72] V half (overlay)
    float* smax = (float*)(smem + 18432);                   // [64][2]
    float* ssum = (float*)(smem + 18944);                   // [64][2]

    // XCD swizzle (272 = 8*34, bijective) + causal half-tile decode
    const int wg = (blockIdx.x & 7) * 34 + (blockIdx.x >> 3);
    int by = 0, c = 0;
    while (c + (by >> 1) + 1 <= wg) { c += (by >> 1) + 1; ++by; }
    const int bx = wg - c;
    const int b = blockIdx.z;

    const bf16* A  = yv + (long long)b * SS * LDY;           // y rows (q role)
    const bf16* Bt = xb + (long long)b * SS * 512;           // x rows (k role)

    const int tid = threadIdx.x;
    const int lane = tid & 63, wave = tid >> 6;               // 4 waves
    const long long m0 = (long long)by * 64;
    const long long n0 = (long long)bx * 128;

    const int rIn2 = lane >> 4;                               // 4 rows per wave-issue
    const int c16 = lane & 15;                                // 16-B chunk within 256-B row
    const int wm0 = (wave >> 1) * 32, wn0 = (wave & 1) * 64;  // 2x2 waves over 64x128
    const int l15 = lane & 15, quad = lane >> 4;
    const int sw7 = l15 & 7;

    floatx4 acc[2][4] = {};

    // prefetch full V chunk V[64][n0..n0+128) to registers: 4 x uint4 per thread
    uint4 vreg[4];
    {
        int j = tid >> 2;
        int ch = tid & 3;
        #pragma unroll
        for (int p = 0; p < 4; ++p)
            vreg[p] = *reinterpret_cast<const uint4*>(
                vt + ((long long)b * DVV + j) * SS + n0 + (ch + p * 4) * 8);
    }

    auto issue = [&](int k0) {
        #pragma unroll
        for (int t0 = 0; t0 < 12; ++t0) {            // 48 slots: 16 A (64 rows) + 32 B (128 rows)
            int t = t0 * 4 + wave;
            if (t < 16) {
                int row = t * 4 + rIn2;              // 0..63
                int col = (c16 ^ (row & 7)) * 8;     // pre-swizzled source chunk
                async_copy16(A + (m0 + row) * (long long)LDY + k0 + col, &As[t * 512]);
            } else {
                int row = (t - 16) * 4 + rIn2;       // 0..127
                int col = (c16 ^ (row & 7)) * 8;
                async_copy16(Bt + (n0 + row) * 512LL + k0 + col, &Bs[(t - 16) * 512]);
            }
        }
    };

    for (int it = 0; it < DIN / BK; ++it) {      // 4 iterations (K=512)
        issue(it * BK);
        __syncthreads();                          // loads landed
        __builtin_amdgcn_s_setprio(1);
        #pragma unroll
        for (int sk = 0; sk < 4; ++sk) {
            const int rchunk = (((sk << 2) | quad) ^ sw7) * 8;
            bf16x8 af[2], bfr[4];
            #pragma unroll
            for (int mi = 0; mi < 2; ++mi)
                af[mi] = *reinterpret_cast<const bf16x8*>(
                    &As[(wm0 + mi * 16 + l15) * BK + rchunk]);
            #pragma unroll
            for (int ni = 0; ni < 4; ++ni)
                bfr[ni] = *reinterpret_cast<const bf16x8*>(
                    &Bs[(wn0 + ni * 16 + l15) * BK + rchunk]);
            #pragma unroll
            for (int mi = 0; mi < 2; ++mi)
                #pragma unroll
                for (int ni = 0; ni < 4; ++ni)
                    acc[mi][ni] = __builtin_amdgcn_mfma_f32_16x16x32_bf16(af[mi], bfr[ni],
                                                                          acc[mi][ni], 0, 0, 0);
        }
        __builtin_amdgcn_s_setprio(0);
        __syncthreads();                          // all reads done before next issue
    }
    // QK done. S in acc: local row = wm0 + mi*16 + quad*4 + r, local col = wn0 + ni*16 + l15.

    // scale + causal mask (tiles straddling the diagonal: n0+127 > m0)
    const bool diag = (n0 + 127 > m0);
    #pragma unroll
    for (int mi = 0; mi < 2; ++mi)
        #pragma unroll
        for (int ni = 0; ni < 4; ++ni)
            #pragma unroll
            for (int r = 0; r < 4; ++r) {
                float v = acc[mi][ni][r] * SCALE;
                if (diag) {
                    int grow = (int)m0 + wm0 + mi * 16 + quad * 4 + r;
                    int gcol = (int)n0 + wn0 + ni * 16 + l15;
                    if (gcol > grow) v = -INFINITY;
                }
                acc[mi][ni][r] = v;
            }

    // row max within tile (2 col-waves per row)
    float rmax[2][4];
    #pragma unroll
    for (int mi = 0; mi < 2; ++mi)
        #pragma unroll
        for (int r = 0; r < 4; ++r) {
            float m = fmaxf(fmaxf(acc[mi][0][r], acc[mi][1][r]),
                            fmaxf(acc[mi][2][r], acc[mi][3][r]));
            #pragma unroll
            for (int msk = 8; msk >= 1; msk >>= 1) m = fmaxf(m, __shfl_xor(m, msk));
            rmax[mi][r] = m;
            if (l15 == 0) smax[(wm0 + mi * 16 + quad * 4 + r) * 2 + (wave & 1)] = m;
        }
    __syncthreads();
    #pragma unroll
    for (int mi = 0; mi < 2; ++mi)
        #pragma unroll
        for (int r = 0; r < 4; ++r) {
            int row = wm0 + mi * 16 + quad * 4 + r;
            rmax[mi][r] = fmaxf(smax[row * 2], smax[row * 2 + 1]);
        }

    // exp + row sums
    #pragma unroll
    for (int mi = 0; mi < 2; ++mi)
        #pragma unroll
        for (int r = 0; r < 4; ++r) {
            float s = 0.f;
            #pragma unroll
            for (int ni = 0; ni < 4; ++ni) {
                float p = __expf(acc[mi][ni][r] - rmax[mi][r]);
                acc[mi][ni][r] = p;
                s += p;
            }
            #pragma unroll
            for (int msk = 8; msk >= 1; msk >>= 1) s += __shfl_xor(s, msk);
            if (l15 == 0) ssum[(wm0 + mi * 16 + quad * 4 + r) * 2 + (wave & 1)] = s;
        }

    // half 0: even waves (wn0==0) write P~ cols 0..63 into Ps[64][72]
    if ((wave & 1) == 0) {
        #pragma unroll
        for (int mi = 0; mi < 2; ++mi) {
            int row = wm0 + mi * 16 + quad * 4;
            #pragma unroll
            for (int ni = 0; ni < 4; ++ni) {
                int col = ni * 16 + l15;
                #pragma unroll
                for (int r = 0; r < 4; ++r)
                    Ps[(row + r) * 72 + col] =
                        (unsigned short)__bfloat16_as_ushort(__float2bfloat16(acc[mi][ni][r]));
            }
        }
    }
    // write V half 0 (global chunks 0..7) xor-swizzled into Vs[64][72]
    {
        int j = tid >> 2;
        int ch = tid & 3;
        #pragma unroll
        for (int pp = 0; pp < 2; ++pp) {
            int chh = ch + pp * 4;                               // within-half chunk 0..7
            *reinterpret_cast<uint4*>(&Vs[j * 72 + ((chh ^ (j & 7)) * 8)]) = vreg[pp];
        }
    }
    __syncthreads();

    // per-row stats out (m, l) for 64 rows
    if (tid < 64) {
        float m = fmaxf(smax[tid * 2], smax[tid * 2 + 1]);
        float l = ssum[tid * 2] + ssum[tid * 2 + 1];
        long long o = (((long long)b * 16 + bx) * SS + m0 + tid) * 2;
        stats[o] = m;
        stats[o + 1] = l;
    }

    // O' = P~ . V  (M=64, N=64, K=128) in two halves; global k-chunk order 0,1,2,3
    const int wmv = wave * 16;
    floatx4 accO[4] = {};
    __builtin_amdgcn_s_setprio(1);
    #pragma unroll
    for (int sk = 0; sk < 2; ++sk) {                       // half 0: kc = sk
        bf16x8 af = *reinterpret_cast<const bf16x8*>(
            &Ps[(wmv + l15) * 72 + sk * 32 + quad * 8]);
        #pragma unroll
        for (int ni = 0; ni < 4; ++ni) {
            bf16x8 bfv = *reinterpret_cast<const bf16x8*>(
                &Vs[(ni * 16 + l15) * 72 + ((((sk << 2) | quad)) ^ sw7) * 8]);
            accO[ni] = __builtin_amdgcn_mfma_f32_16x16x32_bf16(af, bfv, accO[ni], 0, 0, 0);
        }
    }
    __builtin_amdgcn_s_setprio(0);
    __syncthreads();

    // half 1: odd waves (wn0==64) write P~ cols 64..127; V half 1 (chunks 8..15)
    if ((wave & 1) == 1) {
        #pragma unroll
        for (int mi = 0; mi < 2; ++mi) {
            int row = wm0 + mi * 16 + quad * 4;
            #pragma unroll
            for (int ni = 0; ni < 4; ++ni) {
                int col = ni * 16 + l15;
                #pragma unroll
                for (int r = 0; r < 4; ++r)
                    Ps[(row + r) * 72 + col] =
                        (unsigned short)__bfloat16_as_ushort(__float2bfloat16(acc[mi][ni][r]));
            }
        }
    }
    {
        int j = tid >> 2;
        int ch = tid & 3;
        #pragma unroll
        for (int pp = 0; pp < 2; ++pp) {
            int chh = ch + pp * 4;                               // within-half chunk 0..7
            *reinterpret_cast<uint4*>(&Vs[j * 72 + ((chh ^ (j & 7)) * 8)]) = vreg[2 + pp];
        }
    }
    __syncthreads();

    __builtin_amdgcn_s_setprio(1);
    #pragma unroll
    for (int sk = 0; sk < 2; ++sk) {                       // half 1: kc = 2 + sk
        bf16x8 af = *reinterpret_cast<const bf16x8*>(
            &Ps[(wmv + l15) * 72 + sk * 32 + quad * 8]);
        #pragma unroll
        for (int ni = 0; ni < 4; ++ni) {
            bf16x8 bfv = *reinterpret_cast<const bf16x8*>(
                &Vs[(ni * 16 + l15) * 72 + ((((sk << 2) | quad)) ^ sw7) * 8]);
            accO[ni] = __builtin_amdgcn_mfma_f32_16x16x32_bf16(af, bfv, accO[ni], 0, 0, 0);
        }
    }
    __builtin_amdgcn_s_setprio(0);

    #pragma unroll
    for (int ni = 0; ni < 4; ++ni)
        #pragma unroll
        for (int r = 0; r < 4; ++r)
            part[(((long long)b * 16 + bx) * SS + m0 + wmv + quad * 4 + r) * 64 + ni * 16 + l15]
                = __float2bfloat16(accO[ni][r]);
}

// ---------------- combine k-tile partials (vectorized x8 bf16 loads) ----------------
__global__ __launch_bounds__(256) void combine(const bf16* __restrict__ part,
                                               const float* __restrict__ stats,
                                               float* __restrict__ out) {
    int tid = blockIdx.x * 256 + threadIdx.x;   // over 8192*8
    int row = tid >> 3;
    int col8 = (tid & 7) * 8;
    int b = row >> 11, s = row & (SS - 1);
    int nt = (s >> 7) + 1;                      // live k-tiles for this row

    float m[16], l[16], M = -INFINITY;
    #pragma unroll
    for (int t = 0; t < 16; ++t)
        if (t < nt) {
            long long o = (((long long)b * 16 + t) * SS + s) * 2;
            m[t] = stats[o];
            l[t] = stats[o + 1];
            M = fmaxf(M, m[t]);
        }
    float O[8] = {};
    float L = 0.f;
    #pragma unroll
    for (int t = 0; t < 16; ++t)
        if (t < nt) {
            float wgt = __expf(m[t] - M);
            L += wgt * l[t];
            union { uint4 q; unsigned short u[8]; } ld;
            ld.q = *reinterpret_cast<const uint4*>(
                part + (((long long)b * 16 + t) * SS + s) * 64 + col8);
            #pragma unroll
            for (int j = 0; j < 8; ++j)
                O[j] += wgt * __uint_as_float((unsigned)ld.u[j] << 16);
        }
    float rinv = 1.0f / L;
    float4 o0 = {O[0] * rinv, O[1] * rinv, O[2] * rinv, O[3] * rinv};
    float4 o1 = {O[4] * rinv, O[5] * rinv, O[6] * rinv, O[7] * rinv};
    float4* dst = reinterpret_cast<float4*>(out + (long long)row * 64 + col8);
    dst[0] = o0;
    dst[1] = o1;
}

extern "C" void kernel_launch(void* const* d_in, const int* in_sizes, int n_in,
                              void* d_out, int out_size, void* d_ws, size_t ws_size,
                              hipStream_t stream) {
    const float* x  = (const float*)d_in[0];
    const float* Wq = (const float*)d_in[1];
    const float* Wk = (const float*)d_in[2];
    const float* Wv = (const float*)d_in[3];
    float* out = (float*)d_out;

    char* w = (char*)d_ws;
    bf16* xb   = (bf16*)(w + XB_OFF);
    bf16* wt2  = (bf16*)(w + WT2_OFF);
    float* mtp = (float*)(w + MTP_OFF);
    bf16* yv   = (bf16*)(w + YV_OFF);
    bf16* vt   = (bf16*)(w + VT_OFF);
    bf16* part = (bf16*)(w + PRT_OFF);
    float* stats = (float*)(w + STA_OFF);

    // 1. fused prep + Mt: mt blocks first (latency-bound), x-convert overlaps (memory-bound)
    prep_mt<<<4640, 256, 0, stream>>>(x, Wq, Wk, Wv, xb, wt2, mtp);

    // 2. reduce Mt partials -> wt2 rows 0..511
    reduce_mt<<<65536 / 256, 256, 0, stream>>>((const float4*)mtp, wt2);

    // 3. yv = xb·wt2^T (y cols) + vt written transposed directly from the v N-tile
    gemm_proj<<<640, 256, 0, stream>>>(xb, wt2, yv, vt);

    // 4. fused attention: M=64 x N=128 4-wave tiles, BK=128 (4 drain-iters), grid 1088
    attn_fused<<<dim3(272, 1, BB), 256, 0, stream>>>(yv, xb, vt, part, stats);

    // 5. combine partials -> out
    combine<<<ROWS * 8 / 256, 256, 0, stream>>>(part, stats, out);
}

// Round 10
// 135.634 us; speedup vs baseline: 1.2611x; 1.0058x over previous
//
#include <hip/hip_runtime.h>
#include <hip/hip_bf16.h>
#include <math.h>

using bf16 = __hip_bfloat16;
typedef __bf16 bf16x8 __attribute__((ext_vector_type(8)));
typedef float floatx4 __attribute__((ext_vector_type(4)));

// Problem dims
constexpr int BB = 4, SS = 2048, DIN = 512, DKK = 2048, DVV = 64;
constexpr int ROWS = BB * SS;          // 8192
constexpr int LDY = 640;               // yv row: y(512) | pad(128, garbage ok)

// ---- workspace layout (bytes) ----
constexpr size_t XB_OFF  = 0;                          // bf16 xb  [8192][512]   (8 MB)
constexpr size_t WQB_OFF = XB_OFF  + 8388608;          // (unused)
constexpr size_t WKB_OFF = WQB_OFF + 2097152;          // (unused)
constexpr size_t WT2_OFF = WKB_OFF + 2097152;          // bf16 wt2 [640][512]
constexpr size_t MTP_OFF = WT2_OFF + 655360;           // fp32 mt partials [8][512][512] (8 MB)
constexpr size_t YV_OFF  = MTP_OFF + 8388608;          // bf16 yv  [8192][640]   (10 MB)
constexpr size_t VT_OFF  = YV_OFF  + 10485760;         // bf16 vt  [4][64][2048] (1 MB)
constexpr size_t PRT_OFF = VT_OFF  + 1048576;          // bf16 O' partials [4][16][2048][64] (16 MB)
constexpr size_t STA_OFF = PRT_OFF + 16777216;         // fp32 stats [4][16][2048][2] (1 MB)

__device__ __forceinline__ void async_copy16(const bf16* g, const unsigned short* l) {
    __builtin_amdgcn_global_load_lds((const __attribute__((address_space(1))) void*)g,
                                     (__attribute__((address_space(3))) void*)l, 16, 0, 0);
}

// ---------------- fused prep + Mt GEMM -------------------------------------------------
// blocks [0,512):     Mt split-K GEMM (64x64 tiles, 4-wave), staging DIRECTLY from fp32
//                     Wq/Wk with inline bf16 convert (identical RNE rounding -> Mt bit-identical).
// blocks [512,4608):  x -> xb bf16 convert
// blocks [4608,4640): Wv transpose -> wt2 rows 512..575
__global__ __launch_bounds__(256) void prep_mt(const float* __restrict__ x,
                                               const float* __restrict__ Wq,
                                               const float* __restrict__ Wk,
                                               const float* __restrict__ Wv,
                                               bf16* __restrict__ xb,
                                               bf16* __restrict__ wt2,
                                               float* __restrict__ Cp) {
    __shared__ __align__(16) char sm[16384];
    const int bid = blockIdx.x;
    const int tid = threadIdx.x;

    if (bid < 512) {
        unsigned short* As = (unsigned short*)sm;            // 64x64 bf16 (8 KB)
        unsigned short* Bs = (unsigned short*)(sm + 8192);   // 64x64 bf16 (8 KB)
        const int lane = tid & 63, wave = tid >> 6;

        // 512 = 8 XCD x 64; z = split-K plane
        const int wg = (bid & 7) * 64 + (bid >> 3);
        const int z = wg >> 6;
        const int tile = wg & 63;
        const long long m0 = (long long)(tile >> 3) * 64;
        const long long n0 = (long long)(tile & 7) * 64;
        const int koff = z * 256;

        const int rIn = lane >> 3;
        const int cSwzE = ((lane & 7) ^ rIn) * 8;            // pre-swizzled source col (elements)
        const int wm0 = (wave >> 1) * 32, wn0 = (wave & 1) * 32;
        const int l15 = lane & 15, quad = lane >> 4;
        const int sw7 = l15 & 7;

        floatx4 acc[2][2] = {};

        for (int k0 = koff; k0 < koff + 256; k0 += 64) {
            #pragma unroll
            for (int t0 = 0; t0 < 4; ++t0) {                 // 16 slots: 8 A(Wk) + 8 B(Wq)
                int t = t0 * 4 + wave;
                const float* src = (t < 8)
                    ? Wk + (m0 + t * 8 + rIn) * 2048LL + k0 + cSwzE
                    : Wq + (n0 + (t - 8) * 8 + rIn) * 2048LL + k0 + cSwzE;
                float4 f0 = *reinterpret_cast<const float4*>(src);
                float4 f1 = *reinterpret_cast<const float4*>(src + 4);
                union { bf16 h[8]; uint4 u; } cv;
                cv.h[0] = __float2bfloat16(f0.x);
                cv.h[1] = __float2bfloat16(f0.y);
                cv.h[2] = __float2bfloat16(f0.z);
                cv.h[3] = __float2bfloat16(f0.w);
                cv.h[4] = __float2bfloat16(f1.x);
                cv.h[5] = __float2bfloat16(f1.y);
                cv.h[6] = __float2bfloat16(f1.z);
                cv.h[7] = __float2bfloat16(f1.w);
                unsigned short* dst = (t < 8) ? &As[t * 512 + lane * 8]
                                              : &Bs[(t - 8) * 512 + lane * 8];
                *reinterpret_cast<uint4*>(dst) = cv.u;
            }
            __syncthreads();
            #pragma unroll
            for (int sk = 0; sk < 2; ++sk) {
                const int rchunk = (((sk << 2) | quad) ^ sw7) * 8;
                bf16x8 af[2], bfr[2];
                #pragma unroll
                for (int mi = 0; mi < 2; ++mi)
                    af[mi] = *reinterpret_cast<const bf16x8*>(&As[(wm0 + mi * 16 + l15) * 64 + rchunk]);
                #pragma unroll
                for (int ni = 0; ni < 2; ++ni)
                    bfr[ni] = *reinterpret_cast<const bf16x8*>(&Bs[(wn0 + ni * 16 + l15) * 64 + rchunk]);
                #pragma unroll
                for (int mi = 0; mi < 2; ++mi)
                    #pragma unroll
                    for (int ni = 0; ni < 2; ++ni)
                        acc[mi][ni] = __builtin_amdgcn_mfma_f32_16x16x32_bf16(af[mi], bfr[ni],
                                                                              acc[mi][ni], 0, 0, 0);
            }
            __syncthreads();
        }

        float* C = Cp + (long long)z * 262144;
        #pragma unroll
        for (int mi = 0; mi < 2; ++mi) {
            long long row0 = m0 + wm0 + mi * 16 + quad * 4;
            #pragma unroll
            for (int ni = 0; ni < 2; ++ni) {
                long long col = n0 + wn0 + ni * 16 + l15;
                #pragma unroll
                for (int r = 0; r < 4; ++r)
                    C[(row0 + r) * 512 + col] = acc[mi][ni][r];
            }
        }
    } else if (bid < 4608) {
        int i = (bid - 512) * 256 + tid;                     // over 1048576 float4 groups
        float4 v = reinterpret_cast<const float4*>(x)[i];
        union { bf16 h[4]; ushort4 u; } cv;
        cv.h[0] = __float2bfloat16(v.x);
        cv.h[1] = __float2bfloat16(v.y);
        cv.h[2] = __float2bfloat16(v.z);
        cv.h[3] = __float2bfloat16(v.w);
        reinterpret_cast<ushort4*>(xb)[i] = cv.u;
    } else {
        float (*tile)[33] = (float (*)[33])sm;               // 32x33 fp32 (4224 B)
        int idx = bid - 4608;                                // 0..31
        int n0 = (idx & 1) * 32;
        int k0 = (idx >> 1) * 32;
        int nn = tid & 31, kk8 = tid >> 5;
        #pragma unroll
        for (int p = 0; p < 4; ++p) {
            int k = p * 8 + kk8;
            tile[k][nn] = Wv[(long long)(k0 + k) * 64 + n0 + nn];
        }
        __syncthreads();
        int kk = tid & 31, nn8 = tid >> 5;
        #pragma unroll
        for (int p = 0; p < 4; ++p) {
            int n = p * 8 + nn8;
            wt2[(long long)(512 + n0 + n) * 512 + k0 + kk] = __float2bfloat16(tile[kk][n]);
        }
    }
}

// ---------------- reduce Mt partials -> wt2 rows 0..511 (bf16) ----------------
__global__ __launch_bounds__(256) void reduce_mt(const float4* __restrict__ part,
                                                 bf16* __restrict__ wt2) {
    int i = blockIdx.x * 256 + threadIdx.x;          // over 65536 float4 groups
    float4 s = {0.f, 0.f, 0.f, 0.f};
    #pragma unroll
    for (int t = 0; t < 8; ++t) {
        float4 a = part[(long long)t * 65536 + i];
        s.x += a.x; s.y += a.y; s.z += a.z; s.w += a.w;
    }
    union { bf16 h[4]; ushort4 u; } cv;
    cv.h[0] = __float2bfloat16(s.x);
    cv.h[1] = __float2bfloat16(s.y);
    cv.h[2] = __float2bfloat16(s.z);
    cv.h[3] = __float2bfloat16(s.w);
    reinterpret_cast<ushort4*>(wt2)[i] = cv.u;
}

// ---------------- yv GEMM: yv[8192][0..512) = xb . wt2^T, K=512 ----------------
// 64x128 tiles, 640 blocks, vt fused transpose on n-tile 4
__global__ __launch_bounds__(256) void gemm_proj(const bf16* __restrict__ A,
                                                 const bf16* __restrict__ Bt,
                                                 bf16* __restrict__ C,
                                                 bf16* __restrict__ vt) {
    __shared__ __align__(16) unsigned short As[8 * 512];    // 64 rows (8 KB)
    __shared__ __align__(16) unsigned short Bs[16 * 512];   // 128 rows (16 KB)

    const int tid = threadIdx.x;
    const int lane = tid & 63, wave = tid >> 6;      // 4 waves

    // bijective XCD swizzle: 640 blocks, q = 80; m-major enumeration
    const int wg = (blockIdx.x & 7) * 80 + (blockIdx.x >> 3);
    const long long m0 = (long long)(wg / 5) * 64;
    const int ntile = wg % 5;
    const long long n0 = (long long)ntile * 128;

    const int rIn = lane >> 3;
    const int cSwz = ((lane & 7) ^ rIn) * 8;
    const int wm0 = (wave >> 1) * 32, wn0 = (wave & 1) * 64;
    const int l15 = lane & 15, quad = lane >> 4;
    const int sw7 = l15 & 7;

    floatx4 acc[2][4] = {};

    for (int k0 = 0; k0 < DIN; k0 += 64) {
        #pragma unroll
        for (int t0 = 0; t0 < 6; ++t0) {             // 24 slots: 8 A (64 rows) + 16 B (128 rows)
            int t = t0 * 4 + wave;
            if (t < 8)
                async_copy16(A + (m0 + t * 8 + rIn) * (long long)DIN + k0 + cSwz, &As[t * 512]);
            else
                async_copy16(Bt + (n0 + (t - 8) * 8 + rIn) * (long long)DIN + k0 + cSwz,
                             &Bs[(t - 8) * 512]);
        }
        __syncthreads();
        #pragma unroll
        for (int sk = 0; sk < 2; ++sk) {
            const int rchunk = (((sk << 2) | quad) ^ sw7) * 8;
            bf16x8 af[2], bfr[4];
            #pragma unroll
            for (int mi = 0; mi < 2; ++mi)
                af[mi] = *reinterpret_cast<const bf16x8*>(&As[(wm0 + mi * 16 + l15) * 64 + rchunk]);
            #pragma unroll
            for (int ni = 0; ni < 4; ++ni)
                bfr[ni] = *reinterpret_cast<const bf16x8*>(&Bs[(wn0 + ni * 16 + l15) * 64 + rchunk]);
            #pragma unroll
            for (int mi = 0; mi < 2; ++mi)
                #pragma unroll
                for (int ni = 0; ni < 4; ++ni)
                    acc[mi][ni] = __builtin_amdgcn_mfma_f32_16x16x32_bf16(af[mi], bfr[ni],
                                                                          acc[mi][ni], 0, 0, 0);
        }
        __syncthreads();
    }

    if (ntile < 4) {
        #pragma unroll
        for (int mi = 0; mi < 2; ++mi) {
            long long row0 = m0 + wm0 + mi * 16 + quad * 4;
            #pragma unroll
            for (int ni = 0; ni < 4; ++ni) {
                long long col = n0 + wn0 + ni * 16 + l15;
                #pragma unroll
                for (int r = 0; r < 4; ++r)
                    C[(row0 + r) * (long long)LDY + col] = __float2bfloat16(acc[mi][ni][r]);
            }
        }
    } else if (!(wave & 1)) {
        const int b = (int)(m0 >> 11);
        const int sbase = ((int)m0 & 2047) + wm0;
        #pragma unroll
        for (int mi = 0; mi < 2; ++mi) {
            int s0 = sbase + mi * 16 + quad * 4;
            #pragma unroll
            for (int ni = 0; ni < 4; ++ni) {
                int j = ni * 16 + l15;
                union { bf16 h[4]; ushort4 u; } cv;
                #pragma unroll
                for (int r = 0; r < 4; ++r)
                    cv.h[r] = __float2bfloat16(acc[mi][ni][r]);
                *reinterpret_cast<ushort4*>(vt + ((long long)(b * DVV + j)) * SS + s0) = cv.u;
            }
        }
    }
}

// ---------------- fused causal attention tile, M=64 x N=128, 4-wave, BK=128 ----------------
__global__ __launch_bounds__(256) void attn_fused(const bf16* __restrict__ yv,
                                                  const bf16* __restrict__ xb,
                                                  const bf16* __restrict__ vt,
                                                  bf16* __restrict__ part,
                                                  float* __restrict__ stats) {
    constexpr int BK = 128;
    constexpr float SCALE = 0.022097086912079608f;   // 1/sqrt(2048)

    __shared__ __align__(16) char smem[49152];
    unsigned short* As = (unsigned short*)smem;             // [64][128] QK A (16 KB)
    unsigned short* Bs = (unsigned short*)(smem + 16384);   // [128][128] QK B (32 KB)
    unsigned short* Ps = (unsigned short*)smem;             // [64][72] P~ half (overlay, post-QK)
    unsigned short* Vs = (unsigned short*)(smem + 9216);    // [64][72] V half (overlay)
    float* smax = (float*)(smem + 18432);                   // [64][2]
    float* ssum = (float*)(smem + 18944);                   // [64][2]

    // XCD swizzle (272 = 8*34, bijective) + causal half-tile decode
    const int wg = (blockIdx.x & 7) * 34 + (blockIdx.x >> 3);
    int by = 0, c = 0;
    while (c + (by >> 1) + 1 <= wg) { c += (by >> 1) + 1; ++by; }
    const int bx = wg - c;
    const int b = blockIdx.z;

    const bf16* A  = yv + (long long)b * SS * LDY;           // y rows (q role)
    const bf16* Bt = xb + (long long)b * SS * 512;           // x rows (k role)

    const int tid = threadIdx.x;
    const int lane = tid & 63, wave = tid >> 6;               // 4 waves
    const long long m0 = (long long)by * 64;
    const long long n0 = (long long)bx * 128;

    const int rIn2 = lane >> 4;                               // 4 rows per wave-issue
    const int c16 = lane & 15;                                // 16-B chunk within 256-B row
    const int wm0 = (wave >> 1) * 32, wn0 = (wave & 1) * 64;  // 2x2 waves over 64x128
    const int l15 = lane & 15, quad = lane >> 4;
    const int sw7 = l15 & 7;

    floatx4 acc[2][4] = {};

    // prefetch full V chunk V[64][n0..n0+128) to registers: 4 x uint4 per thread
    uint4 vreg[4];
    {
        int j = tid >> 2;
        int ch = tid & 3;
        #pragma unroll
        for (int p = 0; p < 4; ++p)
            vreg[p] = *reinterpret_cast<const uint4*>(
                vt + ((long long)b * DVV + j) * SS + n0 + (ch + p * 4) * 8);
    }

    auto issue = [&](int k0) {
        #pragma unroll
        for (int t0 = 0; t0 < 12; ++t0) {            // 48 slots: 16 A (64 rows) + 32 B (128 rows)
            int t = t0 * 4 + wave;
            if (t < 16) {
                int row = t * 4 + rIn2;              // 0..63
                int col = (c16 ^ (row & 7)) * 8;     // pre-swizzled source chunk
                async_copy16(A + (m0 + row) * (long long)LDY + k0 + col, &As[t * 512]);
            } else {
                int row = (t - 16) * 4 + rIn2;       // 0..127
                int col = (c16 ^ (row & 7)) * 8;
                async_copy16(Bt + (n0 + row) * 512LL + k0 + col, &Bs[(t - 16) * 512]);
            }
        }
    };

    for (int it = 0; it < DIN / BK; ++it) {      // 4 iterations (K=512)
        issue(it * BK);
        __syncthreads();                          // loads landed
        __builtin_amdgcn_s_setprio(1);
        #pragma unroll
        for (int sk = 0; sk < 4; ++sk) {
            const int rchunk = (((sk << 2) | quad) ^ sw7) * 8;
            bf16x8 af[2], bfr[4];
            #pragma unroll
            for (int mi = 0; mi < 2; ++mi)
                af[mi] = *reinterpret_cast<const bf16x8*>(
                    &As[(wm0 + mi * 16 + l15) * BK + rchunk]);
            #pragma unroll
            for (int ni = 0; ni < 4; ++ni)
                bfr[ni] = *reinterpret_cast<const bf16x8*>(
                    &Bs[(wn0 + ni * 16 + l15) * BK + rchunk]);
            #pragma unroll
            for (int mi = 0; mi < 2; ++mi)
                #pragma unroll
                for (int ni = 0; ni < 4; ++ni)
                    acc[mi][ni] = __builtin_amdgcn_mfma_f32_16x16x32_bf16(af[mi], bfr[ni],
                                                                          acc[mi][ni], 0, 0, 0);
        }
        __builtin_amdgcn_s_setprio(0);
        __syncthreads();                          // all reads done before next issue
    }
    // QK done. S in acc: local row = wm0 + mi*16 + quad*4 + r, local col = wn0 + ni*16 + l15.

    // scale + causal mask (tiles straddling the diagonal: n0+127 > m0)
    const bool diag = (n0 + 127 > m0);
    #pragma unroll
    for (int mi = 0; mi < 2; ++mi)
        #pragma unroll
        for (int ni = 0; ni < 4; ++ni)
            #pragma unroll
            for (int r = 0; r < 4; ++r) {
                float v = acc[mi][ni][r] * SCALE;
                if (diag) {
                    int grow = (int)m0 + wm0 + mi * 16 + quad * 4 + r;
                    int gcol = (int)n0 + wn0 + ni * 16 + l15;
                    if (gcol > grow) v = -INFINITY;
                }
                acc[mi][ni][r] = v;
            }

    // row max within tile (2 col-waves per row)
    float rmax[2][4];
    #pragma unroll
    for (int mi = 0; mi < 2; ++mi)
        #pragma unroll
        for (int r = 0; r < 4; ++r) {
            float m = fmaxf(fmaxf(acc[mi][0][r], acc[mi][1][r]),
                            fmaxf(acc[mi][2][r], acc[mi][3][r]));
            #pragma unroll
            for (int msk = 8; msk >= 1; msk >>= 1) m = fmaxf(m, __shfl_xor(m, msk));
            rmax[mi][r] = m;
            if (l15 == 0) smax[(wm0 + mi * 16 + quad * 4 + r) * 2 + (wave & 1)] = m;
        }
    __syncthreads();
    #pragma unroll
    for (int mi = 0; mi < 2; ++mi)
        #pragma unroll
        for (int r = 0; r < 4; ++r) {
            int row = wm0 + mi * 16 + quad * 4 + r;
            rmax[mi][r] = fmaxf(smax[row * 2], smax[row * 2 + 1]);
        }

    // exp + row sums
    #pragma unroll
    for (int mi = 0; mi < 2; ++mi)
        #pragma unroll
        for (int r = 0; r < 4; ++r) {
            float s = 0.f;
            #pragma unroll
            for (int ni = 0; ni < 4; ++ni) {
                float p = __expf(acc[mi][ni][r] - rmax[mi][r]);
                acc[mi][ni][r] = p;
                s += p;
            }
            #pragma unroll
            for (int msk = 8; msk >= 1; msk >>= 1) s += __shfl_xor(s, msk);
            if (l15 == 0) ssum[(wm0 + mi * 16 + quad * 4 + r) * 2 + (wave & 1)] = s;
        }

    // half 0: even waves (wn0==0) write P~ cols 0..63 into Ps[64][72]
    if ((wave & 1) == 0) {
        #pragma unroll
        for (int mi = 0; mi < 2; ++mi) {
            int row = wm0 + mi * 16 + quad * 4;
            #pragma unroll
            for (int ni = 0; ni < 4; ++ni) {
                int col = ni * 16 + l15;
                #pragma unroll
                for (int r = 0; r < 4; ++r)
                    Ps[(row + r) * 72 + col] =
                        (unsigned short)__bfloat16_as_ushort(__float2bfloat16(acc[mi][ni][r]));
            }
        }
    }
    // write V half 0 (global chunks 0..7) xor-swizzled into Vs[64][72]
    {
        int j = tid >> 2;
        int ch = tid & 3;
        #pragma unroll
        for (int pp = 0; pp < 2; ++pp) {
            int chh = ch + pp * 4;                               // within-half chunk 0..7
            *reinterpret_cast<uint4*>(&Vs[j * 72 + ((chh ^ (j & 7)) * 8)]) = vreg[pp];
        }
    }
    __syncthreads();

    // per-row stats out (m, l) for 64 rows
    if (tid < 64) {
        float m = fmaxf(smax[tid * 2], smax[tid * 2 + 1]);
        float l = ssum[tid * 2] + ssum[tid * 2 + 1];
        long long o = (((long long)b * 16 + bx) * SS + m0 + tid) * 2;
        stats[o] = m;
        stats[o + 1] = l;
    }

    // O' = P~ . V  (M=64, N=64, K=128) in two halves; global k-chunk order 0,1,2,3
    const int wmv = wave * 16;
    floatx4 accO[4] = {};
    __builtin_amdgcn_s_setprio(1);
    #pragma unroll
    for (int sk = 0; sk < 2; ++sk) {                       // half 0: kc = sk
        bf16x8 af = *reinterpret_cast<const bf16x8*>(
            &Ps[(wmv + l15) * 72 + sk * 32 + quad * 8]);
        #pragma unroll
        for (int ni = 0; ni < 4; ++ni) {
            bf16x8 bfv = *reinterpret_cast<const bf16x8*>(
                &Vs[(ni * 16 + l15) * 72 + ((((sk << 2) | quad)) ^ sw7) * 8]);
            accO[ni] = __builtin_amdgcn_mfma_f32_16x16x32_bf16(af, bfv, accO[ni], 0, 0, 0);
        }
    }
    __builtin_amdgcn_s_setprio(0);
    __syncthreads();

    // half 1: odd waves (wn0==64) write P~ cols 64..127; V half 1 (chunks 8..15)
    if ((wave & 1) == 1) {
        #pragma unroll
        for (int mi = 0; mi < 2; ++mi) {
            int row = wm0 + mi * 16 + quad * 4;
            #pragma unroll
            for (int ni = 0; ni < 4; ++ni) {
                int col = ni * 16 + l15;
                #pragma unroll
                for (int r = 0; r < 4; ++r)
                    Ps[(row + r) * 72 + col] =
                        (unsigned short)__bfloat16_as_ushort(__float2bfloat16(acc[mi][ni][r]));
            }
        }
    }
    {
        int j = tid >> 2;
        int ch = tid & 3;
        #pragma unroll
        for (int pp = 0; pp < 2; ++pp) {
            int chh = ch + pp * 4;                               // within-half chunk 0..7
            *reinterpret_cast<uint4*>(&Vs[j * 72 + ((chh ^ (j & 7)) * 8)]) = vreg[2 + pp];
        }
    }
    __syncthreads();

    __builtin_amdgcn_s_setprio(1);
    #pragma unroll
    for (int sk = 0; sk < 2; ++sk) {                       // half 1: kc = 2 + sk
        bf16x8 af = *reinterpret_cast<const bf16x8*>(
            &Ps[(wmv + l15) * 72 + sk * 32 + quad * 8]);
        #pragma unroll
        for (int ni = 0; ni < 4; ++ni) {
            bf16x8 bfv = *reinterpret_cast<const bf16x8*>(
                &Vs[(ni * 16 + l15) * 72 + ((((sk << 2) | quad)) ^ sw7) * 8]);
            accO[ni] = __builtin_amdgcn_mfma_f32_16x16x32_bf16(af, bfv, accO[ni], 0, 0, 0);
        }
    }
    __builtin_amdgcn_s_setprio(0);

    #pragma unroll
    for (int ni = 0; ni < 4; ++ni)
        #pragma unroll
        for (int r = 0; r < 4; ++r)
            part[(((long long)b * 16 + bx) * SS + m0 + wmv + quad * 4 + r) * 64 + ni * 16 + l15]
                = __float2bfloat16(accO[ni][r]);
}

// ---------------- combine k-tile partials (vectorized x8 bf16 loads) ----------------
__global__ __launch_bounds__(256) void combine(const bf16* __restrict__ part,
                                               const float* __restrict__ stats,
                                               float* __restrict__ out) {
    int tid = blockIdx.x * 256 + threadIdx.x;   // over 8192*8
    int row = tid >> 3;
    int col8 = (tid & 7) * 8;
    int b = row >> 11, s = row & (SS - 1);
    int nt = (s >> 7) + 1;                      // live k-tiles for this row

    float m[16], l[16], M = -INFINITY;
    #pragma unroll
    for (int t = 0; t < 16; ++t)
        if (t < nt) {
            long long o = (((long long)b * 16 + t) * SS + s) * 2;
            m[t] = stats[o];
            l[t] = stats[o + 1];
            M = fmaxf(M, m[t]);
        }
    float O[8] = {};
    float L = 0.f;
    #pragma unroll
    for (int t = 0; t < 16; ++t)
        if (t < nt) {
            float wgt = __expf(m[t] - M);
            L += wgt * l[t];
            union { uint4 q; unsigned short u[8]; } ld;
            ld.q = *reinterpret_cast<const uint4*>(
                part + (((long long)b * 16 + t) * SS + s) * 64 + col8);
            #pragma unroll
            for (int j = 0; j < 8; ++j)
                O[j] += wgt * __uint_as_float((unsigned)ld.u[j] << 16);
        }
    float rinv = 1.0f / L;
    float4 o0 = {O[0] * rinv, O[1] * rinv, O[2] * rinv, O[3] * rinv};
    float4 o1 = {O[4] * rinv, O[5] * rinv, O[6] * rinv, O[7] * rinv};
    float4* dst = reinterpret_cast<float4*>(out + (long long)row * 64 + col8);
    dst[0] = o0;
    dst[1] = o1;
}

extern "C" void kernel_launch(void* const* d_in, const int* in_sizes, int n_in,
                              void* d_out, int out_size, void* d_ws, size_t ws_size,
                              hipStream_t stream) {
    const float* x  = (const float*)d_in[0];
    const float* Wq = (const float*)d_in[1];
    const float* Wk = (const float*)d_in[2];
    const float* Wv = (const float*)d_in[3];
    float* out = (float*)d_out;

    char* w = (char*)d_ws;
    bf16* xb   = (bf16*)(w + XB_OFF);
    bf16* wt2  = (bf16*)(w + WT2_OFF);
    float* mtp = (float*)(w + MTP_OFF);
    bf16* yv   = (bf16*)(w + YV_OFF);
    bf16* vt   = (bf16*)(w + VT_OFF);
    bf16* part = (bf16*)(w + PRT_OFF);
    float* stats = (float*)(w + STA_OFF);

    // 1. fused prep + Mt: mt blocks first (latency-bound), x-convert overlaps (memory-bound)
    prep_mt<<<4640, 256, 0, stream>>>(x, Wq, Wk, Wv, xb, wt2, mtp);

    // 2. reduce Mt partials -> wt2 rows 0..511
    reduce_mt<<<65536 / 256, 256, 0, stream>>>((const float4*)mtp, wt2);

    // 3. yv = xb·wt2^T (y cols) + vt written transposed directly from the v N-tile
    gemm_proj<<<640, 256, 0, stream>>>(xb, wt2, yv, vt);

    // 4. fused attention: M=64 x N=128 4-wave tiles, BK=128 (4 drain-iters), grid 1088
    attn_fused<<<dim3(272, 1, BB), 256, 0, stream>>>(yv, xb, vt, part, stats);

    // 5. combine partials -> out
    combine<<<ROWS * 8 / 256, 256, 0, stream>>>(part, stats, out);
}